// Round 7
// baseline (489.284 us; speedup 1.0000x reference)
//
#include <hip/hip_runtime.h>

#define TT   110          // max_seq_len
#define BBD  256          // num dialogues
#define NND  28160        // TT*BBD
#define WIN  10

typedef __bf16 bf16x8 __attribute__((ext_vector_type(8)));
typedef __bf16 bf16x4 __attribute__((ext_vector_type(4)));
typedef float  f32x4  __attribute__((ext_vector_type(4)));

__device__ __forceinline__ int imax(int a, int b){ return a > b ? a : b; }
__device__ __forceinline__ int imin(int a, int b){ return a < b ? a : b; }

// ---------------------------------------------------------------------------
// K0: Wrels[r][f][h] = sum_nb comp[r][nb]*basis[nb][f][h]  (r<8); Wrels[8]=root
// ---------------------------------------------------------------------------
__global__ __launch_bounds__(256) void wrels_k(
    const float* __restrict__ basis, const float* __restrict__ comp,
    const float* __restrict__ root, float* __restrict__ wrels)
{
  int idx = blockIdx.x * 256 + threadIdx.x;        // 9*12800 = 115200
  if (idx >= 115200) return;
  int r = idx / 12800, fh = idx % 12800;
  float v;
  if (r < 8) {
    v = 0.f;
    #pragma unroll
    for (int nb = 0; nb < 30; ++nb) v += comp[r*30 + nb] * basis[nb*12800 + fh];
  } else {
    v = root[fh];
  }
  wrels[idx] = v;
}

// ---------------------------------------------------------------------------
// pgemm: A-register-resident MFMA GEMM. C[M x Ncols] = A*B (+bias, opt ReLU).
// BM=64 rows/block, 256 thr = 4 waves (2M x 2N), wave tile 32x32.
// A fragments for the whole K loaded to REGISTERS once (coalesced 16B/lane);
// loop over NCB column blocks, staging B (64 cols x K, XOR-swizzled) in LDS.
// KSP BUG FIX (round 6): chunks = KS/8 (8 bf16 = 16 B per chunk), rounded to
// multiple of 8; KSP = chunks*8 bf16 per row.
// MODE 1: A=xb bf16 [N x 200],  B=wrels (col-blocked [9][200][64])
// MODE 2: A=[xb|h2] bf16,       B=Wma[264x264]
// MODE 3: A=[agg|h1] bf16,      B=[Wrel ; Wroot2]
// MODE 4: A=att bf16 [N x 264], B=Wl[264x64]
// OUT 0: f32 stride Ncols. OUT 1: bf16 stride Ncols. OUT 2: bf16 hi/lo, stride 288.
// ---------------------------------------------------------------------------
template<int MODE, int KDIM, int NCB, bool RELU, int OUT>
__global__ __launch_bounds__(256) void pgemm_k(
    const void* __restrict__ a0, const void* __restrict__ a1,
    const float* __restrict__ Bp, const float* __restrict__ B2p,
    const float* __restrict__ bias, void* __restrict__ Cv, int Ncols)
{
  constexpr int NK  = (KDIM + 31) >> 5;
  constexpr int KS  = NK << 5;
  constexpr int KSP = (((KS >> 3) + 7) & ~7) << 3;   // bf16 elems per LDS row
  __shared__ __align__(16) __bf16 Bsh[64][KSP];

  const int tid = threadIdx.x;
  const int m0 = blockIdx.x << 6;
  const int wid = tid >> 6, lane = tid & 63;
  const int wm = wid >> 1, wn = wid & 1;
  const int fr = lane & 15;
  const int fk = (lane >> 4) << 3;
  const int row0 = (lane >> 4) << 2;

  // ---- load A fragments into registers (once) ----
  bf16x8 afr[2][NK];
  #pragma unroll
  for (int f = 0; f < 2; ++f) {
    const int ra = m0 + wm*32 + f*16 + fr;
    #pragma unroll
    for (int kt = 0; kt < NK; ++kt) {
      const int ko = (kt << 5) + fk;
      if constexpr (MODE == 1) {
        afr[f][kt] = *(const bf16x8*)((const __bf16*)a0 + (size_t)ra*200 + ko);
      } else if constexpr (MODE == 2) {
        afr[f][kt] = (ko < 200)
              ? *(const bf16x8*)((const __bf16*)a0 + (size_t)ra*200 + ko)
              : *(const bf16x8*)((const __bf16*)a1 + (size_t)ra*64 + ko - 200);
      } else if constexpr (MODE == 3) {
        afr[f][kt] = (ko < 64)
              ? *(const bf16x8*)((const __bf16*)a0 + (size_t)ra*64 + ko)
              : *(const bf16x8*)((const __bf16*)a1 + (size_t)ra*64 + ko - 64);
      } else {
        afr[f][kt] = *(const bf16x8*)((const __bf16*)a0 + (size_t)ra*264 + ko);
      }
    }
  }

  for (int cb = 0; cb < NCB; ++cb) {
    const int n0 = cb << 6;
    // ---- stage B tile (f32 -> bf16), transposed+swizzled: Bsh[col][k] ----
    {
      const int col = tid & 63;
      const int gc = n0 + col;
      #pragma unroll
      for (int k4 = (tid >> 6) << 2; k4 < KSP; k4 += 16) {
        bf16x4 v;
        #pragma unroll
        for (int e = 0; e < 4; ++e) {
          const int gk = k4 + e;
          float x = 0.f;
          if (gk < KDIM && gc < Ncols) {
            if constexpr (MODE == 1)      x = Bp[cb*12800 + gk*64 + col];
            else if constexpr (MODE == 2) x = Bp[gk*264 + gc];
            else if constexpr (MODE == 3) x = (gk < 64) ? Bp[gk*64 + gc] : B2p[(gk-64)*64 + gc];
            else                          x = Bp[gk*64 + gc];
          }
          v[e] = (__bf16)x;
        }
        const int sw = ((((k4 >> 3) ^ (col & 7)) << 3) | (k4 & 7));
        *(bf16x4*)&Bsh[col][sw] = v;
      }
    }
    __syncthreads();

    f32x4 acc[2][2];
    #pragma unroll
    for (int f = 0; f < 2; ++f)
      #pragma unroll
      for (int g = 0; g < 2; ++g) acc[f][g] = (f32x4){0.f,0.f,0.f,0.f};

    #pragma unroll
    for (int kt = 0; kt < NK; ++kt) {
      const int ko = (kt << 5) + fk;
      bf16x8 bfv[2];
      #pragma unroll
      for (int g = 0; g < 2; ++g) {
        const int rb_ = wn*32 + g*16 + fr;
        bfv[g] = *(const bf16x8*)&Bsh[rb_][(((ko >> 3) ^ (rb_ & 7)) << 3)];
      }
      #pragma unroll
      for (int f = 0; f < 2; ++f)
        #pragma unroll
        for (int g = 0; g < 2; ++g)
          acc[f][g] = __builtin_amdgcn_mfma_f32_16x16x32_bf16(afr[f][kt], bfv[g], acc[f][g], 0, 0, 0);
    }

    // ---- epilogue: D col=lane&15, row=(lane>>4)*4+reg ----
    #pragma unroll
    for (int g = 0; g < 2; ++g) {
      const int col = n0 + wn*32 + g*16 + fr;
      if (col < Ncols) {
        const float bv = bias ? bias[col] : 0.f;
        #pragma unroll
        for (int f = 0; f < 2; ++f) {
          const int gm0 = m0 + wm*32 + f*16 + row0;
          #pragma unroll
          for (int r2 = 0; r2 < 4; ++r2) {
            float v = acc[f][g][r2] + bv;
            if (RELU) v = fmaxf(v, 0.f);
            const int gm = gm0 + r2;
            if constexpr (OUT == 0) {
              ((float*)Cv)[(size_t)gm * Ncols + col] = v;
            } else if constexpr (OUT == 1) {
              ((__bf16*)Cv)[(size_t)gm * Ncols + col] = (__bf16)v;
            } else {
              __bf16* Cb = (__bf16*)Cv;
              const size_t o = (size_t)gm * 288 + col;
              const __bf16 hi = (__bf16)v;
              Cb[o] = hi;
              Cb[(size_t)288 * NND + o] = (__bf16)(v - (float)hi);
            }
          }
        }
      }
    }
    __syncthreads();
  }
}

// ---------------------------------------------------------------------------
// pgemm mode-0 specialization: source-major A (m = t*256+b), coalesced float4;
// C-row remapped to node order (b*110+t) at the epilogue.
// ---------------------------------------------------------------------------
__global__ __launch_bounds__(256) void pgemm0_k(
    const float* __restrict__ p0, const float* __restrict__ p1,
    const float* __restrict__ p2, const float* __restrict__ Bp,
    const float* __restrict__ bias, __bf16* __restrict__ C)
{
  constexpr int NK = 10, KSP = 320;   // K=300 -> KS=320, 40 chunks (mult of 8)
  __shared__ __align__(16) __bf16 Bsh[64][KSP];

  const int tid = threadIdx.x;
  const int m0 = blockIdx.x << 6;
  const int wid = tid >> 6, lane = tid & 63;
  const int wm = wid >> 1, wn = wid & 1;
  const int fr = lane & 15;
  const int fk = (lane >> 4) << 3;
  const int row0 = (lane >> 4) << 2;

  bf16x8 afr[2][NK];
  #pragma unroll
  for (int f = 0; f < 2; ++f) {
    const int ra = m0 + wm*32 + f*16 + fr;       // ra = t*256+b (source-major)
    const size_t ab = (size_t)ra * 100;
    #pragma unroll
    for (int kt = 0; kt < NK; ++kt) {
      float4 u[2];
      #pragma unroll
      for (int h = 0; h < 2; ++h) {
        const int gk4 = (kt << 5) + fk + (h << 2);
        if (gk4 < 100)       u[h] = *(const float4*)&p0[ab + gk4];
        else if (gk4 < 200)  u[h] = *(const float4*)&p1[ab + gk4 - 100];
        else if (gk4 < 300)  u[h] = *(const float4*)&p2[ab + gk4 - 200];
        else                 u[h] = make_float4(0.f,0.f,0.f,0.f);
      }
      afr[f][kt] = (bf16x8){(__bf16)u[0].x,(__bf16)u[0].y,(__bf16)u[0].z,(__bf16)u[0].w,
                            (__bf16)u[1].x,(__bf16)u[1].y,(__bf16)u[1].z,(__bf16)u[1].w};
    }
  }

  for (int cb = 0; cb < 4; ++cb) {
    const int n0 = cb << 6;
    {
      const int col = tid & 63;
      const int gc = n0 + col;
      #pragma unroll
      for (int k4 = (tid >> 6) << 2; k4 < KSP; k4 += 16) {
        bf16x4 v;
        #pragma unroll
        for (int e = 0; e < 4; ++e) {
          const int gk = k4 + e;
          v[e] = (__bf16)((gk < 300 && gc < 200) ? Bp[gk*200 + gc] : 0.f);
        }
        const int sw = ((((k4 >> 3) ^ (col & 7)) << 3) | (k4 & 7));
        *(bf16x4*)&Bsh[col][sw] = v;
      }
    }
    __syncthreads();

    f32x4 acc[2][2];
    #pragma unroll
    for (int f = 0; f < 2; ++f)
      #pragma unroll
      for (int g = 0; g < 2; ++g) acc[f][g] = (f32x4){0.f,0.f,0.f,0.f};

    #pragma unroll
    for (int kt = 0; kt < NK; ++kt) {
      const int ko = (kt << 5) + fk;
      bf16x8 bfv[2];
      #pragma unroll
      for (int g = 0; g < 2; ++g) {
        const int rb_ = wn*32 + g*16 + fr;
        bfv[g] = *(const bf16x8*)&Bsh[rb_][(((ko >> 3) ^ (rb_ & 7)) << 3)];
      }
      #pragma unroll
      for (int f = 0; f < 2; ++f)
        #pragma unroll
        for (int g = 0; g < 2; ++g)
          acc[f][g] = __builtin_amdgcn_mfma_f32_16x16x32_bf16(afr[f][kt], bfv[g], acc[f][g], 0, 0, 0);
    }

    #pragma unroll
    for (int g = 0; g < 2; ++g) {
      const int col = n0 + wn*32 + g*16 + fr;
      if (col < 200) {
        const float bv = bias[col];
        #pragma unroll
        for (int f = 0; f < 2; ++f) {
          const int gm0 = m0 + wm*32 + f*16 + row0;
          #pragma unroll
          for (int r2 = 0; r2 < 4; ++r2) {
            const int gm = gm0 + r2;                       // gm = t*256+b
            const int orow = (gm & 255) * TT + (gm >> 8);  // node = b*110+t
            C[(size_t)orow * 200 + col] = (__bf16)(acc[f][g][r2] + bv);
          }
        }
      }
    }
    __syncthreads();
  }
}

// ---------------------------------------------------------------------------
// dialog_k: fused RGCN mean-agg + window-sum per dialogue.
// One block (512 thr = 8 waves) per dialogue; h1 kept in LDS f32.
// Emits h1, agg as bf16.
// ---------------------------------------------------------------------------
__global__ __launch_bounds__(512) void dialog_k(
    const __bf16* __restrict__ xr, const int* __restrict__ spk,
    const float* __restrict__ brg, __bf16* __restrict__ h1,
    __bf16* __restrict__ agg)
{
  __shared__ float h1f[TT][64];
  __shared__ int ssp[TT];
  const int b = blockIdx.x;
  const int tid = threadIdx.x;
  if (tid < TT) ssp[tid] = spk[tid * BBD + b];
  __syncthreads();
  const int w = tid >> 6, lane = tid & 63;
  const size_t rb = (size_t)b * TT;
  const float bias = brg[lane];
  for (int t = w; t < TT; t += 8) {
    const int si2 = ssp[t] << 1;
    const int jlo = imax(t - WIN, 0), jhi = imin(t + WIN, TT - 1);
    float a00=0.f, a01=0.f, a10=0.f, a11=0.f;
    int c00=0, c01=0, c10=0, c11=0;
    for (int j = jlo; j <= jhi; ++j) {
      const int s0 = ssp[j];
      const int dir = (j >= t) ? 1 : 0;
      const int r = (s0 << 2) + si2 + dir;
      const float v = (float)xr[(rb + j) * 576 + (r << 6) + lane];
      if (s0) { if (dir) { a11 += v; ++c11; } else { a10 += v; ++c10; } }
      else    { if (dir) { a01 += v; ++c01; } else { a00 += v; ++c00; } }
    }
    float res = a00 / (float)imax(c00,1) + a01 / (float)imax(c01,1)
              + a10 / (float)imax(c10,1) + a11 / (float)imax(c11,1);
    res += (float)xr[(rb + t) * 576 + 512 + lane] + bias;
    h1f[t][lane] = res;
    h1[(rb + t) * 64 + lane] = (__bf16)res;
  }
  __syncthreads();
  for (int t = w; t < TT; t += 8) {
    const int jlo = imax(t - WIN, 0), jhi = imin(t + WIN, TT - 1);
    float a = 0.f;
    for (int j = jlo; j <= jhi; ++j) a += h1f[j][lane];
    agg[(rb + t) * 64 + lane] = (__bf16)a;
  }
}

// ---------------------------------------------------------------------------
// K6: MFMA matching attention. One block (448 thr = 7 waves) per dialogue.
// ---------------------------------------------------------------------------
__global__ __launch_bounds__(448) void attn_mfma_k(
    const __bf16* __restrict__ x, const __bf16* __restrict__ h2,
    const __bf16* __restrict__ Xq, __bf16* __restrict__ att)
{
  __shared__ __align__(16) __bf16 Msh [TT ][272];
  __shared__ __align__(16) __bf16 MTsh[264][136];
  __shared__ __align__(16) __bf16 Ash [112][136];
  const int b = blockIdx.x;
  const int tid = threadIdx.x;
  const size_t nb = (size_t)b * TT;

  for (int idx = tid; idx < TT * 66; idx += 448) {
    const int s = idx / 66, c4 = idx % 66;
    const size_t node = nb + s;
    bf16x4 pk;
    if (c4 < 50) pk = *(const bf16x4*)&x [node * 200 + (c4 << 2)];
    else         pk = *(const bf16x4*)&h2[node * 64 + ((c4 - 50) << 2)];
    *(bf16x4*)&Msh[s][c4 << 2] = pk;
    const int d = c4 << 2;
    MTsh[d+0][s] = pk[0]; MTsh[d+1][s] = pk[1];
    MTsh[d+2][s] = pk[2]; MTsh[d+3][s] = pk[3];
  }
  for (int idx = tid; idx < 264 * 26; idx += 448) MTsh[idx / 26][110 + idx % 26] = (__bf16)0.f;
  for (int idx = tid; idx < 112 * 24; idx += 448) Ash[idx / 24][112 + idx % 24] = (__bf16)0.f;
  __syncthreads();

  const int wid = tid >> 6, lane = tid & 63;
  const int t0 = wid << 4;
  const int fr = lane & 15;
  const int g  = lane >> 4;
  const int fk = g << 3;

  f32x4 sacc[7];
  #pragma unroll
  for (int st = 0; st < 7; ++st) sacc[st] = (f32x4){0.f,0.f,0.f,0.f};
  const int trow = t0 + fr;
  const size_t arow = (nb + (trow < TT ? trow : TT - 1)) * 288;
  const __bf16* XqLo = Xq + (size_t)288 * NND;
  for (int kst = 0; kst < 9; ++kst) {
    const int k0 = kst << 5;
    bf16x8 aqh = *(const bf16x8*)&Xq  [arow + k0 + fk];
    bf16x8 aql = *(const bf16x8*)&XqLo[arow + k0 + fk];
    if (kst == 8 && fk != 0) {
      aqh = (bf16x8){0,0,0,0,0,0,0,0};
      aql = (bf16x8){0,0,0,0,0,0,0,0};
    }
    #pragma unroll
    for (int st = 0; st < 7; ++st) {
      bf16x8 bq;
      if (kst < 8) bq = *(const bf16x8*)&Msh[st*16 + fr][k0 + fk];
      else bq = (fk == 0) ? *(const bf16x8*)&Msh[st*16 + fr][256]
                          : (bf16x8){0,0,0,0,0,0,0,0};
      sacc[st] = __builtin_amdgcn_mfma_f32_16x16x32_bf16(aqh, bq, sacc[st], 0, 0, 0);
      sacc[st] = __builtin_amdgcn_mfma_f32_16x16x32_bf16(aql, bq, sacc[st], 0, 0, 0);
    }
  }

  #pragma unroll
  for (int r = 0; r < 4; ++r) {
    float tv[7];
    #pragma unroll
    for (int st = 0; st < 7; ++st) {
      const float e2 = __expf(2.f * sacc[st][r]);
      tv[st] = 1.f - 2.f / (e2 + 1.f);
    }
    if (fr >= 14) tv[6] = -3.0e38f;
    float mx = fmaxf(fmaxf(fmaxf(tv[0],tv[1]), fmaxf(tv[2],tv[3])),
                     fmaxf(fmaxf(tv[4],tv[5]), tv[6]));
    #pragma unroll
    for (int o = 8; o >= 1; o >>= 1) mx = fmaxf(mx, __shfl_xor(mx, o, 16));
    float e[7], sum = 0.f;
    #pragma unroll
    for (int st = 0; st < 7; ++st) { e[st] = __expf(tv[st] - mx); sum += e[st]; }
    #pragma unroll
    for (int o = 8; o >= 1; o >>= 1) sum += __shfl_xor(sum, o, 16);
    const float inv = 1.f / sum;
    const int tr = t0 + (g << 2) + r;
    #pragma unroll
    for (int st = 0; st < 7; ++st) Ash[tr][st*16 + fr] = (__bf16)(e[st] * inv);
  }
  __syncthreads();

  const int tr2 = t0 + (g << 2);
  for (int dt = 0; dt < 17; ++dt) {
    const int d0 = dt << 4;
    f32x4 pacc = (f32x4){0.f,0.f,0.f,0.f};
    #pragma unroll
    for (int kst = 0; kst < 4; ++kst) {
      const int k0 = kst << 5;
      const bf16x8 pa = *(const bf16x8*)&Ash [t0 + fr][k0 + fk];
      const bf16x8 pb = *(const bf16x8*)&MTsh[d0 + fr][k0 + fk];
      pacc = __builtin_amdgcn_mfma_f32_16x16x32_bf16(pa, pb, pacc, 0, 0, 0);
    }
    const int col = d0 + fr;
    if (col < 264) {
      #pragma unroll
      for (int r = 0; r < 4; ++r) {
        const int t = tr2 + r;
        if (t < TT) att[(nb + t) * 264 + col] = (__bf16)pacc[r];
      }
    }
  }
}

// ---------------------------------------------------------------------------
// K7b: logits + log_softmax. 8 lanes per node (7 classes), 32 nodes/block.
// ---------------------------------------------------------------------------
__global__ __launch_bounds__(256) void logits_k(
    const float* __restrict__ hid, const float* __restrict__ Ws,
    const float* __restrict__ bs, float* __restrict__ out)
{
  const int tid = threadIdx.x;
  const int n = blockIdx.x * 32 + (tid >> 3);
  const int c = tid & 7;
  float lg = -3.0e38f;
  if (c < 7) {
    lg = bs[c];
    const float* hrow = &hid[(size_t)n * 64];
    #pragma unroll
    for (int k = 0; k < 64; ++k) lg += hrow[k] * Ws[k*7 + c];
  }
  float mx = lg;
  #pragma unroll
  for (int o = 4; o >= 1; o >>= 1) mx = fmaxf(mx, __shfl_xor(mx, o, 8));
  float e = (c < 7) ? __expf(lg - mx) : 0.f;
  float sm = e;
  #pragma unroll
  for (int o = 4; o >= 1; o >>= 1) sm += __shfl_xor(sm, o, 8);
  if (c < 7) out[(size_t)n * 7 + c] = lg - mx - __logf(sm);
}

// ---------------------------------------------------------------------------
extern "C" void kernel_launch(void* const* d_in, const int* in_sizes, int n_in,
                              void* d_out, int out_size, void* d_ws, size_t ws_size,
                              hipStream_t stream)
{
  const float* textf  = (const float*)d_in[0];
  const float* acouf  = (const float*)d_in[1];
  const float* visuf  = (const float*)d_in[2];
  const int*   spk    = (const int*)  d_in[3];
  const float* Wf     = (const float*)d_in[4];
  const float* bfv    = (const float*)d_in[5];
  const float* basis  = (const float*)d_in[6];
  const float* comp   = (const float*)d_in[7];
  const float* root   = (const float*)d_in[8];
  const float* brg    = (const float*)d_in[9];
  const float* Wrel   = (const float*)d_in[10];
  const float* brel   = (const float*)d_in[11];
  const float* Wroot2 = (const float*)d_in[12];
  const float* Wma    = (const float*)d_in[13];
  const float* bma    = (const float*)d_in[14];
  const float* Wl     = (const float*)d_in[15];
  const float* bl     = (const float*)d_in[16];
  const float* Wsm    = (const float*)d_in[17];
  const float* bsm    = (const float*)d_in[18];

  float* ws = (float*)d_ws;
  float*  wrels = ws;                               // 115,200 f32
  __bf16* xb    = (__bf16*)(ws + 115200);           // N*200 bf16 = 2,816,000 f32
  __bf16* xr    = (__bf16*)(ws + 2931200);          // N*576 bf16 = 8,110,080 f32
  __bf16* h1b   = (__bf16*)(ws + 11041280);         // N*64 bf16 = 901,120 f32
  __bf16* aggb  = (__bf16*)(ws + 11942400);         // N*64 bf16 = 901,120 f32
  __bf16* h2    = (__bf16*)(ws + 12843520);         // N*64 bf16 = 901,120 f32
  __bf16* Xqb   = (__bf16*)(ws + 13744640);         // 2*N*288 bf16 = 8,110,080 f32
  float*  hid   = ws + 21854720;                    // N*64 f32 = 1,802,240
  __bf16* attb  = (__bf16*)(ws + 2931200);          // alias xr (dead after dialog_k)
  float*  outp  = (float*)d_out;

  wrels_k<<<450, 256, 0, stream>>>(basis, comp, root, wrels);
  pgemm0_k<<<440, 256, 0, stream>>>(textf, acouf, visuf, Wf, bfv, xb);
  pgemm_k<1,200,9,false,1><<<440, 256, 0, stream>>>(xb, nullptr, wrels, nullptr, nullptr, xr, 576);
  dialog_k<<<256, 512, 0, stream>>>(xr, spk, brg, h1b, aggb);
  pgemm_k<3,128,1,false,1><<<440, 256, 0, stream>>>(aggb, h1b, Wrel, Wroot2, brel, h2, 64);
  pgemm_k<2,264,5,false,2><<<440, 256, 0, stream>>>(xb, h2, Wma, nullptr, bma, Xqb, 264);
  attn_mfma_k<<<256, 448, 0, stream>>>(xb, h2, Xqb, attb);
  pgemm_k<4,264,1,true,0><<<440, 256, 0, stream>>>(attb, nullptr, Wl, nullptr, bl, hid, 64);
  logits_k<<<880, 256, 0, stream>>>(hid, Wsm, bsm, outp);
}

// Round 8
// 335.317 us; speedup vs baseline: 1.4592x; 1.4592x over previous
//
#include <hip/hip_runtime.h>

#define TT   110          // max_seq_len
#define BBD  256          // num dialogues
#define NND  28160        // TT*BBD
#define WIN  10

typedef __bf16 bf16x8 __attribute__((ext_vector_type(8)));
typedef __bf16 bf16x4 __attribute__((ext_vector_type(4)));
typedef float  f32x4  __attribute__((ext_vector_type(4)));

__device__ __forceinline__ int imax(int a, int b){ return a > b ? a : b; }
__device__ __forceinline__ int imin(int a, int b){ return a < b ? a : b; }

// All per-node matrices are SOURCE-MAJOR: row m = t*256 + b  (node n = b*110+t).

// ---------------------------------------------------------------------------
// K0: Wrels[r][f][h] = sum_nb comp[r][nb]*basis[nb][f][h]  (r<8); Wrels[8]=root
// ---------------------------------------------------------------------------
__global__ __launch_bounds__(256) void wrels_k(
    const float* __restrict__ basis, const float* __restrict__ comp,
    const float* __restrict__ root, float* __restrict__ wrels)
{
  int idx = blockIdx.x * 256 + threadIdx.x;        // 9*12800 = 115200
  if (idx >= 115200) return;
  int r = idx / 12800, fh = idx % 12800;
  float v;
  if (r < 8) {
    v = 0.f;
    #pragma unroll
    for (int nb = 0; nb < 30; ++nb) v += comp[r*30 + nb] * basis[nb*12800 + fh];
  } else {
    v = root[fh];
  }
  wrels[idx] = v;
}

// ---------------------------------------------------------------------------
// bgemm: B-resident MFMA GEMM (round-5 proven structure, BM=64).
// Block = 64 rows x 64 cols, 256 thr = 4 waves (2M x 2N), wave tile 32x32.
// B staged to LDS ONCE (XOR-swizzled) -> ONE barrier; A fragments straight
// from global per K-tile. Grid = 440*NCB, bijective XCD-chunked swizzle.
// MODE 0: A=concat(textf,acouf,visuf) f32 source-major (contiguous!), B=Wf
// MODE 1: A=xb bf16 [N x 200], B=wrels col-blocked [9][200][64]
// MODE 2: A=[xb|h2] bf16,      B=Wma[264x264]
// OUT 1: bf16 stride Ncols. OUT 2: bf16 hi+lo planes, stride 288.
// ---------------------------------------------------------------------------
template<int MODE, int KDIM, int NCB, int OUT>
__global__ __launch_bounds__(256) void bgemm_k(
    const void* __restrict__ a0, const void* __restrict__ a1,
    const void* __restrict__ a2, const float* __restrict__ Bp,
    const float* __restrict__ bias, void* __restrict__ Cv, int Ncols)
{
  constexpr int NK  = (KDIM + 31) >> 5;
  constexpr int KS  = NK << 5;
  constexpr int KSP = (((KS >> 3) + 7) & ~7) << 3;   // bf16 elems per LDS row
  __shared__ __align__(16) __bf16 Bsh[64][KSP];

  const int tid = threadIdx.x;
  constexpr int NWT = 440 * NCB;                     // all uses: NWT % 8 == 0
  constexpr int q = NWT >> 3;
  const int bid = blockIdx.x;
  const int w = (bid & 7) * q + (bid >> 3);          // bijective XCD swizzle
  const int m0 = (w / NCB) << 6;
  const int cb = w % NCB;
  const int n0 = cb << 6;

  // ---- stage B (f32 -> bf16), swizzled, once ----
  {
    const int col = tid & 63;
    const int gc = n0 + col;
    for (int k4 = (tid >> 6) << 2; k4 < KSP; k4 += 16) {
      bf16x4 v;
      #pragma unroll
      for (int e = 0; e < 4; ++e) {
        const int gk = k4 + e;
        float x = 0.f;
        if (gk < KDIM && gc < Ncols) {
          if constexpr (MODE == 0)      x = Bp[gk*200 + gc];
          else if constexpr (MODE == 1) x = Bp[cb*12800 + gk*64 + col];
          else                          x = Bp[gk*264 + gc];
        }
        v[e] = (__bf16)x;
      }
      const int sw = ((((k4 >> 3) ^ (col & 7)) << 3) | (k4 & 7));
      *(bf16x4*)&Bsh[col][sw] = v;
    }
  }
  __syncthreads();

  const int wid = tid >> 6, lane = tid & 63;
  const int wm = wid >> 1, wn = wid & 1;
  const int fr = lane & 15;
  const int fk = (lane >> 4) << 3;
  const int row0 = (lane >> 4) << 2;

  f32x4 acc[2][2];
  #pragma unroll
  for (int f = 0; f < 2; ++f)
    #pragma unroll
    for (int g = 0; g < 2; ++g) acc[f][g] = (f32x4){0.f,0.f,0.f,0.f};

  #pragma unroll
  for (int kt = 0; kt < NK; ++kt) {
    const int ko = (kt << 5) + fk;
    bf16x8 af[2];
    #pragma unroll
    for (int f = 0; f < 2; ++f) {
      const int ra = m0 + wm*32 + f*16 + fr;
      if constexpr (MODE == 0) {
        const size_t ab = (size_t)ra * 100;
        float4 u[2];
        #pragma unroll
        for (int h = 0; h < 2; ++h) {
          const int g4 = ko + (h << 2);
          if (g4 < 100)      u[h] = *(const float4*)((const float*)a0 + ab + g4);
          else if (g4 < 200) u[h] = *(const float4*)((const float*)a1 + ab + g4 - 100);
          else if (g4 < 300) u[h] = *(const float4*)((const float*)a2 + ab + g4 - 200);
          else               u[h] = make_float4(0.f,0.f,0.f,0.f);
        }
        af[f] = (bf16x8){(__bf16)u[0].x,(__bf16)u[0].y,(__bf16)u[0].z,(__bf16)u[0].w,
                         (__bf16)u[1].x,(__bf16)u[1].y,(__bf16)u[1].z,(__bf16)u[1].w};
      } else if constexpr (MODE == 1) {
        af[f] = *(const bf16x8*)((const __bf16*)a0 + (size_t)ra*200 + ko);
      } else { // MODE 2
        af[f] = (ko < 200)
              ? *(const bf16x8*)((const __bf16*)a0 + (size_t)ra*200 + ko)
              : *(const bf16x8*)((const __bf16*)a1 + (size_t)ra*64 + (ko - 200));
      }
    }
    bf16x8 bfv[2];
    #pragma unroll
    for (int g = 0; g < 2; ++g) {
      const int rb_ = wn*32 + g*16 + fr;
      bfv[g] = *(const bf16x8*)&Bsh[rb_][(((ko >> 3) ^ (rb_ & 7)) << 3)];
    }
    #pragma unroll
    for (int f = 0; f < 2; ++f)
      #pragma unroll
      for (int g = 0; g < 2; ++g)
        acc[f][g] = __builtin_amdgcn_mfma_f32_16x16x32_bf16(af[f], bfv[g], acc[f][g], 0, 0, 0);
  }

  // ---- epilogue: D col=lane&15, row=(lane>>4)*4+reg ----
  #pragma unroll
  for (int g = 0; g < 2; ++g) {
    const int col = n0 + wn*32 + g*16 + fr;
    if (col < Ncols) {
      const float bv = bias ? bias[col] : 0.f;
      #pragma unroll
      for (int f = 0; f < 2; ++f) {
        const int gm0 = m0 + wm*32 + f*16 + row0;
        #pragma unroll
        for (int r2 = 0; r2 < 4; ++r2) {
          const float v = acc[f][g][r2] + bv;
          const int gm = gm0 + r2;
          if constexpr (OUT == 1) {
            ((__bf16*)Cv)[(size_t)gm * Ncols + col] = (__bf16)v;
          } else {
            __bf16* Cb = (__bf16*)Cv;
            const size_t o = (size_t)gm * 288 + col;
            const __bf16 hi = (__bf16)v;
            Cb[o] = hi;
            Cb[(size_t)288 * NND + o] = (__bf16)(v - (float)hi);
          }
        }
      }
    }
  }
}

// ---------------------------------------------------------------------------
// dialog_k: fused RGCN mean-agg + window-sum + GraphConv GEMM per dialogue.
// One block (512 thr = 8 waves) per dialogue. h1, agg live in f32 LDS only;
// [Wrel;Wroot2] staged bf16 (swizzled); h2 = [agg|h1]@[Wrel;Wroot2] + brel
// emitted bf16 source-major. No h1/agg global traffic at all.
// ---------------------------------------------------------------------------
__global__ __launch_bounds__(512) void dialog_k(
    const __bf16* __restrict__ xr, const int* __restrict__ spk,
    const float* __restrict__ brg, const float* __restrict__ Wrel,
    const float* __restrict__ Wroot2, const float* __restrict__ brel,
    __bf16* __restrict__ h2)
{
  __shared__ float h1f [TT][68];
  __shared__ float aggf[TT][68];
  __shared__ __align__(16) __bf16 Bsh[64][128];
  __shared__ int ssp[TT];
  const int b = blockIdx.x;
  const int tid = threadIdx.x;
  if (tid < TT) ssp[tid] = spk[tid * BBD + b];
  { // stage [Wrel;Wroot2] 128x64 -> bf16 swizzled
    const int col = tid & 63;
    for (int k4 = (tid >> 6) << 2; k4 < 128; k4 += 32) {
      bf16x4 v;
      #pragma unroll
      for (int e = 0; e < 4; ++e) {
        const int gk = k4 + e;
        v[e] = (__bf16)((gk < 64) ? Wrel[gk*64 + col] : Wroot2[(gk-64)*64 + col]);
      }
      const int sw = ((((k4 >> 3) ^ (col & 7)) << 3) | (k4 & 7));
      *(bf16x4*)&Bsh[col][sw] = v;
    }
  }
  __syncthreads();
  const int w8 = tid >> 6, lane = tid & 63;
  const float bias = brg[lane];
  // ---- phase 1: h1 ----
  for (int t = w8; t < TT; t += 8) {
    const int si2 = ssp[t] << 1;
    const int jlo = imax(t - WIN, 0), jhi = imin(t + WIN, TT - 1);
    float a00=0.f, a01=0.f, a10=0.f, a11=0.f;
    int c00=0, c01=0, c10=0, c11=0;
    for (int j = jlo; j <= jhi; ++j) {
      const int s0 = ssp[j];
      const int dir = (j >= t) ? 1 : 0;
      const int r = (s0 << 2) + si2 + dir;
      const float v = (float)xr[((size_t)j * BBD + b) * 576 + (r << 6) + lane];
      if (s0) { if (dir) { a11 += v; ++c11; } else { a10 += v; ++c10; } }
      else    { if (dir) { a01 += v; ++c01; } else { a00 += v; ++c00; } }
    }
    float res = a00 / (float)imax(c00,1) + a01 / (float)imax(c01,1)
              + a10 / (float)imax(c10,1) + a11 / (float)imax(c11,1);
    res += (float)xr[((size_t)t * BBD + b) * 576 + 512 + lane] + bias;
    h1f[t][lane] = res;
  }
  __syncthreads();
  // ---- phase 2: agg = window-sum(h1) ----
  for (int t = w8; t < TT; t += 8) {
    const int jlo = imax(t - WIN, 0), jhi = imin(t + WIN, TT - 1);
    float a = 0.f;
    for (int j = jlo; j <= jhi; ++j) a += h1f[j][lane];
    aggf[t][lane] = a;
  }
  __syncthreads();
  // ---- phase 3: h2 = [agg|h1] @ [Wrel;Wroot2] + brel ----
  const int wm = w8 >> 1, wn = w8 & 1;
  const int fr = lane & 15, fk = (lane >> 4) << 3, row0 = (lane >> 4) << 2;
  f32x4 acc[2][2];
  #pragma unroll
  for (int f = 0; f < 2; ++f)
    #pragma unroll
    for (int g = 0; g < 2; ++g) acc[f][g] = (f32x4){0.f,0.f,0.f,0.f};
  #pragma unroll
  for (int kt = 0; kt < 4; ++kt) {
    const int ko = (kt << 5) + fk;
    bf16x8 af[2];
    #pragma unroll
    for (int f = 0; f < 2; ++f) {
      const int tr = wm*32 + f*16 + fr;
      if (tr < TT) {
        const float* src = (ko < 64) ? &aggf[tr][ko] : &h1f[tr][ko - 64];
        const float4 u0 = ((const float4*)src)[0];
        const float4 u1 = ((const float4*)src)[1];
        af[f] = (bf16x8){(__bf16)u0.x,(__bf16)u0.y,(__bf16)u0.z,(__bf16)u0.w,
                         (__bf16)u1.x,(__bf16)u1.y,(__bf16)u1.z,(__bf16)u1.w};
      } else af[f] = (bf16x8){0,0,0,0,0,0,0,0};
    }
    bf16x8 bfv[2];
    #pragma unroll
    for (int g = 0; g < 2; ++g) {
      const int rb_ = wn*32 + g*16 + fr;
      bfv[g] = *(const bf16x8*)&Bsh[rb_][(((ko >> 3) ^ (rb_ & 7)) << 3)];
    }
    #pragma unroll
    for (int f = 0; f < 2; ++f)
      #pragma unroll
      for (int g = 0; g < 2; ++g)
        acc[f][g] = __builtin_amdgcn_mfma_f32_16x16x32_bf16(af[f], bfv[g], acc[f][g], 0, 0, 0);
  }
  #pragma unroll
  for (int g = 0; g < 2; ++g) {
    const int col = wn*32 + g*16 + fr;
    const float bv = brel[col];
    #pragma unroll
    for (int f = 0; f < 2; ++f) {
      const int t0_ = wm*32 + f*16 + row0;
      #pragma unroll
      for (int r2 = 0; r2 < 4; ++r2) {
        const int t = t0_ + r2;
        if (t < TT) h2[((size_t)t * BBD + b) * 64 + col] = (__bf16)(acc[f][g][r2] + bv);
      }
    }
  }
}

// ---------------------------------------------------------------------------
// attn: MFMA matching attention, one block (448 thr = 7 waves) per dialogue.
// Source-major row indexing; otherwise identical to round 5 (proven fast).
// ---------------------------------------------------------------------------
__global__ __launch_bounds__(448) void attn_mfma_k(
    const __bf16* __restrict__ x, const __bf16* __restrict__ h2,
    const __bf16* __restrict__ Xq, __bf16* __restrict__ att)
{
  __shared__ __align__(16) __bf16 Msh [TT ][272];
  __shared__ __align__(16) __bf16 MTsh[264][136];
  __shared__ __align__(16) __bf16 Ash [112][136];
  const int b = blockIdx.x;
  const int tid = threadIdx.x;

  for (int idx = tid; idx < TT * 66; idx += 448) {
    const int s = idx / 66, c4 = idx % 66;
    const size_t node = (size_t)s * BBD + b;
    bf16x4 pk;
    if (c4 < 50) pk = *(const bf16x4*)&x [node * 200 + (c4 << 2)];
    else         pk = *(const bf16x4*)&h2[node * 64 + ((c4 - 50) << 2)];
    *(bf16x4*)&Msh[s][c4 << 2] = pk;
    const int d = c4 << 2;
    MTsh[d+0][s] = pk[0]; MTsh[d+1][s] = pk[1];
    MTsh[d+2][s] = pk[2]; MTsh[d+3][s] = pk[3];
  }
  for (int idx = tid; idx < 264 * 26; idx += 448) MTsh[idx / 26][110 + idx % 26] = (__bf16)0.f;
  for (int idx = tid; idx < 112 * 24; idx += 448) Ash[idx / 24][112 + idx % 24] = (__bf16)0.f;
  __syncthreads();

  const int wid = tid >> 6, lane = tid & 63;
  const int t0 = wid << 4;
  const int fr = lane & 15;
  const int g  = lane >> 4;
  const int fk = g << 3;

  f32x4 sacc[7];
  #pragma unroll
  for (int st = 0; st < 7; ++st) sacc[st] = (f32x4){0.f,0.f,0.f,0.f};
  const int trow = t0 + fr;
  const size_t arow = ((size_t)(trow < TT ? trow : TT - 1) * BBD + b) * 288;
  const __bf16* XqLo = Xq + (size_t)288 * NND;
  for (int kst = 0; kst < 9; ++kst) {
    const int k0 = kst << 5;
    bf16x8 aqh = *(const bf16x8*)&Xq  [arow + k0 + fk];
    bf16x8 aql = *(const bf16x8*)&XqLo[arow + k0 + fk];
    if (kst == 8 && fk != 0) {
      aqh = (bf16x8){0,0,0,0,0,0,0,0};
      aql = (bf16x8){0,0,0,0,0,0,0,0};
    }
    #pragma unroll
    for (int st = 0; st < 7; ++st) {
      bf16x8 bq;
      if (kst < 8) bq = *(const bf16x8*)&Msh[st*16 + fr][k0 + fk];
      else bq = (fk == 0) ? *(const bf16x8*)&Msh[st*16 + fr][256]
                          : (bf16x8){0,0,0,0,0,0,0,0};
      sacc[st] = __builtin_amdgcn_mfma_f32_16x16x32_bf16(aqh, bq, sacc[st], 0, 0, 0);
      sacc[st] = __builtin_amdgcn_mfma_f32_16x16x32_bf16(aql, bq, sacc[st], 0, 0, 0);
    }
  }

  #pragma unroll
  for (int r = 0; r < 4; ++r) {
    float tv[7];
    #pragma unroll
    for (int st = 0; st < 7; ++st) {
      const float e2 = __expf(2.f * sacc[st][r]);
      tv[st] = 1.f - 2.f / (e2 + 1.f);
    }
    if (fr >= 14) tv[6] = -3.0e38f;
    float mx = fmaxf(fmaxf(fmaxf(tv[0],tv[1]), fmaxf(tv[2],tv[3])),
                     fmaxf(fmaxf(tv[4],tv[5]), tv[6]));
    #pragma unroll
    for (int o = 8; o >= 1; o >>= 1) mx = fmaxf(mx, __shfl_xor(mx, o, 16));
    float e[7], sum = 0.f;
    #pragma unroll
    for (int st = 0; st < 7; ++st) { e[st] = __expf(tv[st] - mx); sum += e[st]; }
    #pragma unroll
    for (int o = 8; o >= 1; o >>= 1) sum += __shfl_xor(sum, o, 16);
    const float inv = 1.f / sum;
    const int tr = t0 + (g << 2) + r;
    #pragma unroll
    for (int st = 0; st < 7; ++st) Ash[tr][st*16 + fr] = (__bf16)(e[st] * inv);
  }
  __syncthreads();

  const int tr2 = t0 + (g << 2);
  for (int dt = 0; dt < 17; ++dt) {
    const int d0 = dt << 4;
    f32x4 pacc = (f32x4){0.f,0.f,0.f,0.f};
    #pragma unroll
    for (int kst = 0; kst < 4; ++kst) {
      const int k0 = kst << 5;
      const bf16x8 pa = *(const bf16x8*)&Ash [t0 + fr][k0 + fk];
      const bf16x8 pb = *(const bf16x8*)&MTsh[d0 + fr][k0 + fk];
      pacc = __builtin_amdgcn_mfma_f32_16x16x32_bf16(pa, pb, pacc, 0, 0, 0);
    }
    const int col = d0 + fr;
    if (col < 264) {
      #pragma unroll
      for (int r = 0; r < 4; ++r) {
        const int t = tr2 + r;
        if (t < TT) att[((size_t)t * BBD + b) * 264 + col] = (__bf16)pacc[r];
      }
    }
  }
}

// ---------------------------------------------------------------------------
// final_k: fused hidden GEMM (att@Wl+bl, ReLU) + logits + log_softmax.
// BM=64, 256 thr, Wl in LDS once; hidden tile -> LDS; per-row 8-lane softmax.
// ---------------------------------------------------------------------------
__global__ __launch_bounds__(256) void final_k(
    const __bf16* __restrict__ att, const float* __restrict__ Wl,
    const float* __restrict__ bl, const float* __restrict__ Wsm,
    const float* __restrict__ bsm, float* __restrict__ out)
{
  constexpr int KSP = 320;                   // K=264 -> KS=288 -> 40 chunks
  __shared__ __align__(16) __bf16 Bsh[64][KSP];
  __shared__ float hidf[64][68];
  __shared__ float Wssh[64][8];
  const int tid = threadIdx.x;
  const int bid = blockIdx.x;
  const int m0 = ((bid & 7) * 55 + (bid >> 3)) << 6;   // 440 = 8*55
  {
    const int col = tid & 63;
    for (int k4 = (tid >> 6) << 2; k4 < KSP; k4 += 16) {
      bf16x4 v;
      #pragma unroll
      for (int e = 0; e < 4; ++e) {
        const int gk = k4 + e;
        v[e] = (__bf16)((gk < 264) ? Wl[gk*64 + col] : 0.f);
      }
      const int sw = ((((k4 >> 3) ^ (col & 7)) << 3) | (k4 & 7));
      *(bf16x4*)&Bsh[col][sw] = v;
    }
    for (int i = tid; i < 512; i += 256) {
      const int k = i >> 3, c = i & 7;
      Wssh[k][c] = (c < 7) ? Wsm[k*7 + c] : 0.f;
    }
  }
  __syncthreads();
  const int wid = tid >> 6, lane = tid & 63;
  const int wm = wid >> 1, wn = wid & 1;
  const int fr = lane & 15, fk = (lane >> 4) << 3, row0 = (lane >> 4) << 2;
  f32x4 acc[2][2];
  #pragma unroll
  for (int f = 0; f < 2; ++f)
    #pragma unroll
    for (int g = 0; g < 2; ++g) acc[f][g] = (f32x4){0.f,0.f,0.f,0.f};
  #pragma unroll
  for (int kt = 0; kt < 9; ++kt) {
    const int ko = (kt << 5) + fk;
    bf16x8 af[2];
    #pragma unroll
    for (int f = 0; f < 2; ++f) {
      const int ra = m0 + wm*32 + f*16 + fr;
      af[f] = (ko < 264) ? *(const bf16x8*)(att + (size_t)ra*264 + ko)
                         : (bf16x8){0,0,0,0,0,0,0,0};
    }
    bf16x8 bfv[2];
    #pragma unroll
    for (int g = 0; g < 2; ++g) {
      const int rb_ = wn*32 + g*16 + fr;
      bfv[g] = *(const bf16x8*)&Bsh[rb_][(((ko >> 3) ^ (rb_ & 7)) << 3)];
    }
    #pragma unroll
    for (int f = 0; f < 2; ++f)
      #pragma unroll
      for (int g = 0; g < 2; ++g)
        acc[f][g] = __builtin_amdgcn_mfma_f32_16x16x32_bf16(af[f], bfv[g], acc[f][g], 0, 0, 0);
  }
  // hidden tile -> LDS (ReLU + bias)
  #pragma unroll
  for (int g = 0; g < 2; ++g) {
    const int col = wn*32 + g*16 + fr;
    const float bv = bl[col];
    #pragma unroll
    for (int f = 0; f < 2; ++f) {
      const int lr0 = wm*32 + f*16 + row0;
      #pragma unroll
      for (int r2 = 0; r2 < 4; ++r2)
        hidf[lr0 + r2][col] = fmaxf(acc[f][g][r2] + bv, 0.f);
    }
  }
  __syncthreads();
  // logits + log_softmax: 2 passes of 32 rows, 8 lanes per row
  const int c = tid & 7;
  const float bc = (c < 7) ? bsm[c] : 0.f;
  #pragma unroll
  for (int p = 0; p < 2; ++p) {
    const int lr = (p << 5) + (tid >> 3);
    float lg = -3.0e38f;
    if (c < 7) {
      lg = bc;
      #pragma unroll
      for (int k = 0; k < 64; ++k) lg += hidf[lr][k] * Wssh[k][c];
    }
    float mx = lg;
    #pragma unroll
    for (int o = 4; o >= 1; o >>= 1) mx = fmaxf(mx, __shfl_xor(mx, o, 8));
    float e = (c < 7) ? __expf(lg - mx) : 0.f;
    float sm = e;
    #pragma unroll
    for (int o = 4; o >= 1; o >>= 1) sm += __shfl_xor(sm, o, 8);
    if (c < 7) {
      const int gm = m0 + lr;                 // gm = t*256 + b
      const int t = gm >> 8, bb = gm & 255;
      out[((size_t)bb * TT + t) * 7 + c] = lg - mx - __logf(sm);
    }
  }
}

// ---------------------------------------------------------------------------
extern "C" void kernel_launch(void* const* d_in, const int* in_sizes, int n_in,
                              void* d_out, int out_size, void* d_ws, size_t ws_size,
                              hipStream_t stream)
{
  const float* textf  = (const float*)d_in[0];
  const float* acouf  = (const float*)d_in[1];
  const float* visuf  = (const float*)d_in[2];
  const int*   spk    = (const int*)  d_in[3];
  const float* Wf     = (const float*)d_in[4];
  const float* bfv    = (const float*)d_in[5];
  const float* basis  = (const float*)d_in[6];
  const float* comp   = (const float*)d_in[7];
  const float* root   = (const float*)d_in[8];
  const float* brg    = (const float*)d_in[9];
  const float* Wrel   = (const float*)d_in[10];
  const float* brel   = (const float*)d_in[11];
  const float* Wroot2 = (const float*)d_in[12];
  const float* Wma    = (const float*)d_in[13];
  const float* bma    = (const float*)d_in[14];
  const float* Wl     = (const float*)d_in[15];
  const float* bl     = (const float*)d_in[16];
  const float* Wsm    = (const float*)d_in[17];
  const float* bsm    = (const float*)d_in[18];

  float* ws = (float*)d_ws;
  float*  wrels = ws;                               // 115,200 f32
  __bf16* xb    = (__bf16*)(ws + 115200);           // N*200 bf16
  __bf16* xr    = (__bf16*)(ws + 2931200);          // N*576 bf16 (att aliases)
  __bf16* h2    = (__bf16*)(ws + 11041280);         // N*64 bf16
  __bf16* Xqb   = (__bf16*)(ws + 11942400);         // 2*N*288 bf16
  __bf16* attb  = (__bf16*)(ws + 2931200);          // alias xr (dead after dialog_k)
  float*  outp  = (float*)d_out;

  wrels_k<<<450, 256, 0, stream>>>(basis, comp, root, wrels);
  bgemm_k<0,300,4,1><<<1760, 256, 0, stream>>>(textf, acouf, visuf, Wf, bfv, xb, 200);
  bgemm_k<1,200,9,1><<<3960, 256, 0, stream>>>(xb, nullptr, nullptr, wrels, nullptr, xr, 576);
  dialog_k<<<256, 512, 0, stream>>>(xr, spk, brg, Wrel, Wroot2, brel, h2);
  bgemm_k<2,264,5,2><<<2200, 256, 0, stream>>>(xb, h2, nullptr, Wma, bma, Xqb, 264);
  attn_mfma_k<<<256, 448, 0, stream>>>(xb, h2, Xqb, attb);
  final_k<<<440, 256, 0, stream>>>(attb, Wl, bl, Wsm, bsm, outp);
}

// Round 9
// 282.390 us; speedup vs baseline: 1.7327x; 1.1874x over previous
//
#include <hip/hip_runtime.h>

#define TT   110          // max_seq_len
#define BBD  256          // num dialogues
#define NND  28160        // TT*BBD
#define WIN  10

typedef __bf16 bf16x8 __attribute__((ext_vector_type(8)));
typedef __bf16 bf16x4 __attribute__((ext_vector_type(4)));
typedef float  f32x4  __attribute__((ext_vector_type(4)));

__device__ __forceinline__ int imax(int a, int b){ return a > b ? a : b; }
__device__ __forceinline__ int imin(int a, int b){ return a < b ? a : b; }

// All per-node matrices are SOURCE-MAJOR: row m = t*256 + b  (node n = b*110+t).

// ---------------------------------------------------------------------------
// K0: Wrels[r][f][h] = sum_nb comp[r][nb]*basis[nb][f][h]  (r<8); Wrels[8]=root
// ---------------------------------------------------------------------------
__global__ __launch_bounds__(256) void wrels_k(
    const float* __restrict__ basis, const float* __restrict__ comp,
    const float* __restrict__ root, float* __restrict__ wrels)
{
  int idx = blockIdx.x * 256 + threadIdx.x;        // 9*12800 = 115200
  if (idx >= 115200) return;
  int r = idx / 12800, fh = idx % 12800;
  float v;
  if (r < 8) {
    v = 0.f;
    #pragma unroll
    for (int nb = 0; nb < 30; ++nb) v += comp[r*30 + nb] * basis[nb*12800 + fh];
  } else {
    v = root[fh];
  }
  wrels[idx] = v;
}

// ---------------------------------------------------------------------------
// bgemm: B-resident MFMA GEMM (round-5 proven structure, BM=64).
// Block = 64 rows x 64 cols, 256 thr = 4 waves (2M x 2N), wave tile 32x32.
// B staged to LDS ONCE (XOR-swizzled) -> ONE barrier; A fragments straight
// from global per K-tile. Grid = 440*NCB, bijective XCD-chunked swizzle.
// MODE 0: A=concat(textf,acouf,visuf) f32 source-major (contiguous!), B=Wf
// MODE 1: A=xb bf16 [N x 200], B=wrels col-blocked [9][200][64]
// MODE 2: A=[xb|h2] bf16,      B=Wma[264x264]
// OUT 1: bf16 stride Ncols. OUT 2: bf16 hi+lo planes, stride 288.
// ---------------------------------------------------------------------------
template<int MODE, int KDIM, int NCB, int OUT>
__global__ __launch_bounds__(256) void bgemm_k(
    const void* __restrict__ a0, const void* __restrict__ a1,
    const void* __restrict__ a2, const float* __restrict__ Bp,
    const float* __restrict__ bias, void* __restrict__ Cv, int Ncols)
{
  constexpr int NK  = (KDIM + 31) >> 5;
  constexpr int KS  = NK << 5;
  constexpr int KSP = (((KS >> 3) + 7) & ~7) << 3;   // bf16 elems per LDS row
  __shared__ __align__(16) __bf16 Bsh[64][KSP];

  const int tid = threadIdx.x;
  constexpr int NWT = 440 * NCB;                     // all uses: NWT % 8 == 0
  constexpr int q = NWT >> 3;
  const int bid = blockIdx.x;
  const int w = (bid & 7) * q + (bid >> 3);          // bijective XCD swizzle
  const int m0 = (w / NCB) << 6;
  const int cb = w % NCB;
  const int n0 = cb << 6;

  // ---- stage B (f32 -> bf16), swizzled, once ----
  {
    const int col = tid & 63;
    const int gc = n0 + col;
    for (int k4 = (tid >> 6) << 2; k4 < KSP; k4 += 16) {
      bf16x4 v;
      #pragma unroll
      for (int e = 0; e < 4; ++e) {
        const int gk = k4 + e;
        float x = 0.f;
        if (gk < KDIM && gc < Ncols) {
          if constexpr (MODE == 0)      x = Bp[gk*200 + gc];
          else if constexpr (MODE == 1) x = Bp[cb*12800 + gk*64 + col];
          else                          x = Bp[gk*264 + gc];
        }
        v[e] = (__bf16)x;
      }
      const int sw = ((((k4 >> 3) ^ (col & 7)) << 3) | (k4 & 7));
      *(bf16x4*)&Bsh[col][sw] = v;
    }
  }
  __syncthreads();

  const int wid = tid >> 6, lane = tid & 63;
  const int wm = wid >> 1, wn = wid & 1;
  const int fr = lane & 15;
  const int fk = (lane >> 4) << 3;
  const int row0 = (lane >> 4) << 2;

  f32x4 acc[2][2];
  #pragma unroll
  for (int f = 0; f < 2; ++f)
    #pragma unroll
    for (int g = 0; g < 2; ++g) acc[f][g] = (f32x4){0.f,0.f,0.f,0.f};

  #pragma unroll
  for (int kt = 0; kt < NK; ++kt) {
    const int ko = (kt << 5) + fk;
    bf16x8 af[2];
    #pragma unroll
    for (int f = 0; f < 2; ++f) {
      const int ra = m0 + wm*32 + f*16 + fr;
      if constexpr (MODE == 0) {
        const size_t ab = (size_t)ra * 100;
        float4 u[2];
        #pragma unroll
        for (int h = 0; h < 2; ++h) {
          const int g4 = ko + (h << 2);
          if (g4 < 100)      u[h] = *(const float4*)((const float*)a0 + ab + g4);
          else if (g4 < 200) u[h] = *(const float4*)((const float*)a1 + ab + g4 - 100);
          else if (g4 < 300) u[h] = *(const float4*)((const float*)a2 + ab + g4 - 200);
          else               u[h] = make_float4(0.f,0.f,0.f,0.f);
        }
        af[f] = (bf16x8){(__bf16)u[0].x,(__bf16)u[0].y,(__bf16)u[0].z,(__bf16)u[0].w,
                         (__bf16)u[1].x,(__bf16)u[1].y,(__bf16)u[1].z,(__bf16)u[1].w};
      } else if constexpr (MODE == 1) {
        af[f] = *(const bf16x8*)((const __bf16*)a0 + (size_t)ra*200 + ko);
      } else { // MODE 2
        af[f] = (ko < 200)
              ? *(const bf16x8*)((const __bf16*)a0 + (size_t)ra*200 + ko)
              : *(const bf16x8*)((const __bf16*)a1 + (size_t)ra*64 + (ko - 200));
      }
    }
    bf16x8 bfv[2];
    #pragma unroll
    for (int g = 0; g < 2; ++g) {
      const int rb_ = wn*32 + g*16 + fr;
      bfv[g] = *(const bf16x8*)&Bsh[rb_][(((ko >> 3) ^ (rb_ & 7)) << 3)];
    }
    #pragma unroll
    for (int f = 0; f < 2; ++f)
      #pragma unroll
      for (int g = 0; g < 2; ++g)
        acc[f][g] = __builtin_amdgcn_mfma_f32_16x16x32_bf16(af[f], bfv[g], acc[f][g], 0, 0, 0);
  }

  // ---- epilogue: D col=lane&15, row=(lane>>4)*4+reg ----
  #pragma unroll
  for (int g = 0; g < 2; ++g) {
    const int col = n0 + wn*32 + g*16 + fr;
    if (col < Ncols) {
      const float bv = bias ? bias[col] : 0.f;
      #pragma unroll
      for (int f = 0; f < 2; ++f) {
        const int gm0 = m0 + wm*32 + f*16 + row0;
        #pragma unroll
        for (int r2 = 0; r2 < 4; ++r2) {
          const float v = acc[f][g][r2] + bv;
          const int gm = gm0 + r2;
          if constexpr (OUT == 1) {
            ((__bf16*)Cv)[(size_t)gm * Ncols + col] = (__bf16)v;
          } else {
            __bf16* Cb = (__bf16*)Cv;
            const size_t o = (size_t)gm * 288 + col;
            const __bf16 hi = (__bf16)v;
            Cb[o] = hi;
            Cb[(size_t)288 * NND + o] = (__bf16)(v - (float)hi);
          }
        }
      }
    }
  }
}

// ---------------------------------------------------------------------------
// dialog_k: fused RGCN mean-agg + window-sum + GraphConv GEMM per dialogue.
// ROUND 9: xr window data staged to LDS FIRST (bulk, pipelined, coalesced),
// window loop reads LDS. Per j only cols [s0*256, s0*256+256) (the 4 slices
// for r = s0*4+{0..3}) + root slice [512,576) are needed -> Xsh[110][320].
// LDS: 70.4K (Xsh) + 29.9K (h1f) + 29.9K (aggf) + 16K (Bsh) = 143.6 KB.
// ---------------------------------------------------------------------------
__global__ __launch_bounds__(512) void dialog_k(
    const __bf16* __restrict__ xr, const int* __restrict__ spk,
    const float* __restrict__ brg, const float* __restrict__ Wrel,
    const float* __restrict__ Wroot2, const float* __restrict__ brel,
    __bf16* __restrict__ h2)
{
  __shared__ __align__(16) __bf16 Xsh[TT][320];
  __shared__ float h1f [TT][68];
  __shared__ float aggf[TT][68];
  __shared__ __align__(16) __bf16 Bsh[64][128];
  __shared__ int ssp[TT];
  const int b = blockIdx.x;
  const int tid = threadIdx.x;
  if (tid < TT) ssp[tid] = spk[tid * BBD + b];
  { // stage [Wrel;Wroot2] 128x64 -> bf16 swizzled
    const int col = tid & 63;
    for (int k4 = (tid >> 6) << 2; k4 < 128; k4 += 32) {
      bf16x4 v;
      #pragma unroll
      for (int e = 0; e < 4; ++e) {
        const int gk = k4 + e;
        v[e] = (__bf16)((gk < 64) ? Wrel[gk*64 + col] : Wroot2[(gk-64)*64 + col]);
      }
      const int sw = ((((k4 >> 3) ^ (col & 7)) << 3) | (k4 & 7));
      *(bf16x4*)&Bsh[col][sw] = v;
    }
  }
  __syncthreads();      // ssp ready (needed for Xsh source addressing)
  // ---- stage xr slices: per j, 256 relation cols (s0-selected) + 64 root ----
  for (int i = tid << 3; i < TT * 320; i += 512 << 3) {
    const int j = i / 320, off = i - j * 320;
    const size_t base = ((size_t)j * BBD + b) * 576;
    const int col = (off < 256) ? ((ssp[j] << 8) + off) : (256 + off);
    *(bf16x8*)&Xsh[j][off] = *(const bf16x8*)&xr[base + col];
  }
  __syncthreads();
  const int w8 = tid >> 6, lane = tid & 63;
  const float bias = brg[lane];
  // ---- phase 1: h1 (reads LDS only) ----
  for (int t = w8; t < TT; t += 8) {
    const int si2 = ssp[t] << 1;
    const int jlo = imax(t - WIN, 0), jhi = imin(t + WIN, TT - 1);
    float a00=0.f, a01=0.f, a10=0.f, a11=0.f;
    int c00=0, c01=0, c10=0, c11=0;
    for (int j = jlo; j <= jhi; ++j) {
      const int s0 = ssp[j];
      const int dir = (j >= t) ? 1 : 0;
      const float v = (float)Xsh[j][((si2 + dir) << 6) + lane];
      if (s0) { if (dir) { a11 += v; ++c11; } else { a10 += v; ++c10; } }
      else    { if (dir) { a01 += v; ++c01; } else { a00 += v; ++c00; } }
    }
    float res = a00 / (float)imax(c00,1) + a01 / (float)imax(c01,1)
              + a10 / (float)imax(c10,1) + a11 / (float)imax(c11,1);
    res += (float)Xsh[t][256 + lane] + bias;
    h1f[t][lane] = res;
  }
  __syncthreads();
  // ---- phase 2: agg = window-sum(h1) ----
  for (int t = w8; t < TT; t += 8) {
    const int jlo = imax(t - WIN, 0), jhi = imin(t + WIN, TT - 1);
    float a = 0.f;
    for (int j = jlo; j <= jhi; ++j) a += h1f[j][lane];
    aggf[t][lane] = a;
  }
  __syncthreads();
  // ---- phase 3: h2 = [agg|h1] @ [Wrel;Wroot2] + brel ----
  const int wm = w8 >> 1, wn = w8 & 1;
  const int fr = lane & 15, fk = (lane >> 4) << 3, row0 = (lane >> 4) << 2;
  f32x4 acc[2][2];
  #pragma unroll
  for (int f = 0; f < 2; ++f)
    #pragma unroll
    for (int g = 0; g < 2; ++g) acc[f][g] = (f32x4){0.f,0.f,0.f,0.f};
  #pragma unroll
  for (int kt = 0; kt < 4; ++kt) {
    const int ko = (kt << 5) + fk;
    bf16x8 af[2];
    #pragma unroll
    for (int f = 0; f < 2; ++f) {
      const int tr = wm*32 + f*16 + fr;
      if (tr < TT) {
        const float* src = (ko < 64) ? &aggf[tr][ko] : &h1f[tr][ko - 64];
        const float4 u0 = ((const float4*)src)[0];
        const float4 u1 = ((const float4*)src)[1];
        af[f] = (bf16x8){(__bf16)u0.x,(__bf16)u0.y,(__bf16)u0.z,(__bf16)u0.w,
                         (__bf16)u1.x,(__bf16)u1.y,(__bf16)u1.z,(__bf16)u1.w};
      } else af[f] = (bf16x8){0,0,0,0,0,0,0,0};
    }
    bf16x8 bfv[2];
    #pragma unroll
    for (int g = 0; g < 2; ++g) {
      const int rb_ = wn*32 + g*16 + fr;
      bfv[g] = *(const bf16x8*)&Bsh[rb_][(((ko >> 3) ^ (rb_ & 7)) << 3)];
    }
    #pragma unroll
    for (int f = 0; f < 2; ++f)
      #pragma unroll
      for (int g = 0; g < 2; ++g)
        acc[f][g] = __builtin_amdgcn_mfma_f32_16x16x32_bf16(af[f], bfv[g], acc[f][g], 0, 0, 0);
  }
  #pragma unroll
  for (int g = 0; g < 2; ++g) {
    const int col = wn*32 + g*16 + fr;
    const float bv = brel[col];
    #pragma unroll
    for (int f = 0; f < 2; ++f) {
      const int t0_ = wm*32 + f*16 + row0;
      #pragma unroll
      for (int r2 = 0; r2 < 4; ++r2) {
        const int t = t0_ + r2;
        if (t < TT) h2[((size_t)t * BBD + b) * 64 + col] = (__bf16)(acc[f][g][r2] + bv);
      }
    }
  }
}

// ---------------------------------------------------------------------------
// attn: MFMA matching attention, one block (448 thr = 7 waves) per dialogue.
// ---------------------------------------------------------------------------
__global__ __launch_bounds__(448) void attn_mfma_k(
    const __bf16* __restrict__ x, const __bf16* __restrict__ h2,
    const __bf16* __restrict__ Xq, __bf16* __restrict__ att)
{
  __shared__ __align__(16) __bf16 Msh [TT ][272];
  __shared__ __align__(16) __bf16 MTsh[264][136];
  __shared__ __align__(16) __bf16 Ash [112][136];
  const int b = blockIdx.x;
  const int tid = threadIdx.x;

  for (int idx = tid; idx < TT * 66; idx += 448) {
    const int s = idx / 66, c4 = idx % 66;
    const size_t node = (size_t)s * BBD + b;
    bf16x4 pk;
    if (c4 < 50) pk = *(const bf16x4*)&x [node * 200 + (c4 << 2)];
    else         pk = *(const bf16x4*)&h2[node * 64 + ((c4 - 50) << 2)];
    *(bf16x4*)&Msh[s][c4 << 2] = pk;
    const int d = c4 << 2;
    MTsh[d+0][s] = pk[0]; MTsh[d+1][s] = pk[1];
    MTsh[d+2][s] = pk[2]; MTsh[d+3][s] = pk[3];
  }
  for (int idx = tid; idx < 264 * 26; idx += 448) MTsh[idx / 26][110 + idx % 26] = (__bf16)0.f;
  for (int idx = tid; idx < 112 * 24; idx += 448) Ash[idx / 24][112 + idx % 24] = (__bf16)0.f;
  __syncthreads();

  const int wid = tid >> 6, lane = tid & 63;
  const int t0 = wid << 4;
  const int fr = lane & 15;
  const int g  = lane >> 4;
  const int fk = g << 3;

  f32x4 sacc[7];
  #pragma unroll
  for (int st = 0; st < 7; ++st) sacc[st] = (f32x4){0.f,0.f,0.f,0.f};
  const int trow = t0 + fr;
  const size_t arow = ((size_t)(trow < TT ? trow : TT - 1) * BBD + b) * 288;
  const __bf16* XqLo = Xq + (size_t)288 * NND;
  for (int kst = 0; kst < 9; ++kst) {
    const int k0 = kst << 5;
    bf16x8 aqh = *(const bf16x8*)&Xq  [arow + k0 + fk];
    bf16x8 aql = *(const bf16x8*)&XqLo[arow + k0 + fk];
    if (kst == 8 && fk != 0) {
      aqh = (bf16x8){0,0,0,0,0,0,0,0};
      aql = (bf16x8){0,0,0,0,0,0,0,0};
    }
    #pragma unroll
    for (int st = 0; st < 7; ++st) {
      bf16x8 bq;
      if (kst < 8) bq = *(const bf16x8*)&Msh[st*16 + fr][k0 + fk];
      else bq = (fk == 0) ? *(const bf16x8*)&Msh[st*16 + fr][256]
                          : (bf16x8){0,0,0,0,0,0,0,0};
      sacc[st] = __builtin_amdgcn_mfma_f32_16x16x32_bf16(aqh, bq, sacc[st], 0, 0, 0);
      sacc[st] = __builtin_amdgcn_mfma_f32_16x16x32_bf16(aql, bq, sacc[st], 0, 0, 0);
    }
  }

  #pragma unroll
  for (int r = 0; r < 4; ++r) {
    float tv[7];
    #pragma unroll
    for (int st = 0; st < 7; ++st) {
      const float e2 = __expf(2.f * sacc[st][r]);
      tv[st] = 1.f - 2.f / (e2 + 1.f);
    }
    if (fr >= 14) tv[6] = -3.0e38f;
    float mx = fmaxf(fmaxf(fmaxf(tv[0],tv[1]), fmaxf(tv[2],tv[3])),
                     fmaxf(fmaxf(tv[4],tv[5]), tv[6]));
    #pragma unroll
    for (int o = 8; o >= 1; o >>= 1) mx = fmaxf(mx, __shfl_xor(mx, o, 16));
    float e[7], sum = 0.f;
    #pragma unroll
    for (int st = 0; st < 7; ++st) { e[st] = __expf(tv[st] - mx); sum += e[st]; }
    #pragma unroll
    for (int o = 8; o >= 1; o >>= 1) sum += __shfl_xor(sum, o, 16);
    const float inv = 1.f / sum;
    const int tr = t0 + (g << 2) + r;
    #pragma unroll
    for (int st = 0; st < 7; ++st) Ash[tr][st*16 + fr] = (__bf16)(e[st] * inv);
  }
  __syncthreads();

  const int tr2 = t0 + (g << 2);
  for (int dt = 0; dt < 17; ++dt) {
    const int d0 = dt << 4;
    f32x4 pacc = (f32x4){0.f,0.f,0.f,0.f};
    #pragma unroll
    for (int kst = 0; kst < 4; ++kst) {
      const int k0 = kst << 5;
      const bf16x8 pa = *(const bf16x8*)&Ash [t0 + fr][k0 + fk];
      const bf16x8 pb = *(const bf16x8*)&MTsh[d0 + fr][k0 + fk];
      pacc = __builtin_amdgcn_mfma_f32_16x16x32_bf16(pa, pb, pacc, 0, 0, 0);
    }
    const int col = d0 + fr;
    if (col < 264) {
      #pragma unroll
      for (int r = 0; r < 4; ++r) {
        const int t = tr2 + r;
        if (t < TT) att[((size_t)t * BBD + b) * 264 + col] = (__bf16)pacc[r];
      }
    }
  }
}

// ---------------------------------------------------------------------------
// final_k: fused hidden GEMM (att@Wl+bl, ReLU) + logits + log_softmax.
// ---------------------------------------------------------------------------
__global__ __launch_bounds__(256) void final_k(
    const __bf16* __restrict__ att, const float* __restrict__ Wl,
    const float* __restrict__ bl, const float* __restrict__ Wsm,
    const float* __restrict__ bsm, float* __restrict__ out)
{
  constexpr int KSP = 320;                   // K=264 -> KS=288 -> 40 chunks
  __shared__ __align__(16) __bf16 Bsh[64][KSP];
  __shared__ float hidf[64][68];
  __shared__ float Wssh[64][8];
  const int tid = threadIdx.x;
  const int bid = blockIdx.x;
  const int m0 = ((bid & 7) * 55 + (bid >> 3)) << 6;   // 440 = 8*55
  {
    const int col = tid & 63;
    for (int k4 = (tid >> 6) << 2; k4 < KSP; k4 += 16) {
      bf16x4 v;
      #pragma unroll
      for (int e = 0; e < 4; ++e) {
        const int gk = k4 + e;
        v[e] = (__bf16)((gk < 264) ? Wl[gk*64 + col] : 0.f);
      }
      const int sw = ((((k4 >> 3) ^ (col & 7)) << 3) | (k4 & 7));
      *(bf16x4*)&Bsh[col][sw] = v;
    }
    for (int i = tid; i < 512; i += 256) {
      const int k = i >> 3, c = i & 7;
      Wssh[k][c] = (c < 7) ? Wsm[k*7 + c] : 0.f;
    }
  }
  __syncthreads();
  const int wid = tid >> 6, lane = tid & 63;
  const int wm = wid >> 1, wn = wid & 1;
  const int fr = lane & 15, fk = (lane >> 4) << 3, row0 = (lane >> 4) << 2;
  f32x4 acc[2][2];
  #pragma unroll
  for (int f = 0; f < 2; ++f)
    #pragma unroll
    for (int g = 0; g < 2; ++g) acc[f][g] = (f32x4){0.f,0.f,0.f,0.f};
  #pragma unroll
  for (int kt = 0; kt < 9; ++kt) {
    const int ko = (kt << 5) + fk;
    bf16x8 af[2];
    #pragma unroll
    for (int f = 0; f < 2; ++f) {
      const int ra = m0 + wm*32 + f*16 + fr;
      af[f] = (ko < 264) ? *(const bf16x8*)(att + (size_t)ra*264 + ko)
                         : (bf16x8){0,0,0,0,0,0,0,0};
    }
    bf16x8 bfv[2];
    #pragma unroll
    for (int g = 0; g < 2; ++g) {
      const int rb_ = wn*32 + g*16 + fr;
      bfv[g] = *(const bf16x8*)&Bsh[rb_][(((ko >> 3) ^ (rb_ & 7)) << 3)];
    }
    #pragma unroll
    for (int f = 0; f < 2; ++f)
      #pragma unroll
      for (int g = 0; g < 2; ++g)
        acc[f][g] = __builtin_amdgcn_mfma_f32_16x16x32_bf16(af[f], bfv[g], acc[f][g], 0, 0, 0);
  }
  // hidden tile -> LDS (ReLU + bias)
  #pragma unroll
  for (int g = 0; g < 2; ++g) {
    const int col = wn*32 + g*16 + fr;
    const float bv = bl[col];
    #pragma unroll
    for (int f = 0; f < 2; ++f) {
      const int lr0 = wm*32 + f*16 + row0;
      #pragma unroll
      for (int r2 = 0; r2 < 4; ++r2)
        hidf[lr0 + r2][col] = fmaxf(acc[f][g][r2] + bv, 0.f);
    }
  }
  __syncthreads();
  // logits + log_softmax: 2 passes of 32 rows, 8 lanes per row
  const int c = tid & 7;
  const float bc = (c < 7) ? bsm[c] : 0.f;
  #pragma unroll
  for (int p = 0; p < 2; ++p) {
    const int lr = (p << 5) + (tid >> 3);
    float lg = -3.0e38f;
    if (c < 7) {
      lg = bc;
      #pragma unroll
      for (int k = 0; k < 64; ++k) lg += hidf[lr][k] * Wssh[k][c];
    }
    float mx = lg;
    #pragma unroll
    for (int o = 4; o >= 1; o >>= 1) mx = fmaxf(mx, __shfl_xor(mx, o, 8));
    float e = (c < 7) ? __expf(lg - mx) : 0.f;
    float sm = e;
    #pragma unroll
    for (int o = 4; o >= 1; o >>= 1) sm += __shfl_xor(sm, o, 8);
    if (c < 7) {
      const int gm = m0 + lr;                 // gm = t*256 + b
      const int t = gm >> 8, bb = gm & 255;
      out[((size_t)bb * TT + t) * 7 + c] = lg - mx - __logf(sm);
    }
  }
}

// ---------------------------------------------------------------------------
extern "C" void kernel_launch(void* const* d_in, const int* in_sizes, int n_in,
                              void* d_out, int out_size, void* d_ws, size_t ws_size,
                              hipStream_t stream)
{
  const float* textf  = (const float*)d_in[0];
  const float* acouf  = (const float*)d_in[1];
  const float* visuf  = (const float*)d_in[2];
  const int*   spk    = (const int*)  d_in[3];
  const float* Wf     = (const float*)d_in[4];
  const float* bfv    = (const float*)d_in[5];
  const float* basis  = (const float*)d_in[6];
  const float* comp   = (const float*)d_in[7];
  const float* root   = (const float*)d_in[8];
  const float* brg    = (const float*)d_in[9];
  const float* Wrel   = (const float*)d_in[10];
  const float* brel   = (const float*)d_in[11];
  const float* Wroot2 = (const float*)d_in[12];
  const float* Wma    = (const float*)d_in[13];
  const float* bma    = (const float*)d_in[14];
  const float* Wl     = (const float*)d_in[15];
  const float* bl     = (const float*)d_in[16];
  const float* Wsm    = (const float*)d_in[17];
  const float* bsm    = (const float*)d_in[18];

  float* ws = (float*)d_ws;
  float*  wrels = ws;                               // 115,200 f32
  __bf16* xb    = (__bf16*)(ws + 115200);           // N*200 bf16
  __bf16* xr    = (__bf16*)(ws + 2931200);          // N*576 bf16 (att aliases)
  __bf16* h2    = (__bf16*)(ws + 11041280);         // N*64 bf16
  __bf16* Xqb   = (__bf16*)(ws + 11942400);         // 2*N*288 bf16
  __bf16* attb  = (__bf16*)(ws + 2931200);          // alias xr (dead after dialog_k)
  float*  outp  = (float*)d_out;

  wrels_k<<<450, 256, 0, stream>>>(basis, comp, root, wrels);
  bgemm_k<0,300,4,1><<<1760, 256, 0, stream>>>(textf, acouf, visuf, Wf, bfv, xb, 200);
  bgemm_k<1,200,9,1><<<3960, 256, 0, stream>>>(xb, nullptr, nullptr, wrels, nullptr, xr, 576);
  dialog_k<<<256, 512, 0, stream>>>(xr, spk, brg, Wrel, Wroot2, brel, h2);
  bgemm_k<2,264,5,2><<<2200, 256, 0, stream>>>(xb, h2, nullptr, Wma, bma, Xqb, 264);
  attn_mfma_k<<<256, 448, 0, stream>>>(xb, h2, Xqb, attb);
  final_k<<<440, 256, 0, stream>>>(attb, Wl, bl, Wsm, bsm, outp);
}

// Round 10
// 189.036 us; speedup vs baseline: 2.5883x; 1.4938x over previous
//
#include <hip/hip_runtime.h>

#define TT   110          // max_seq_len
#define BBD  256          // num dialogues
#define NND  28160        // TT*BBD
#define WIN  10

typedef __bf16 bf16x8 __attribute__((ext_vector_type(8)));
typedef __bf16 bf16x4 __attribute__((ext_vector_type(4)));
typedef float  f32x4  __attribute__((ext_vector_type(4)));

__device__ __forceinline__ int imax(int a, int b){ return a > b ? a : b; }
__device__ __forceinline__ int imin(int a, int b){ return a < b ? a : b; }

// All per-node matrices are SOURCE-MAJOR: row m = t*256 + b  (node n = b*110+t).
// Weight images (bf16, pre-swizzled per 64-col tile, row=col, KSP elems):
//   Wfimg [4][64][320] @ img+0
//   wrimg [9][64][256] @ img+81920
//   Wmaimg[5][64][320] @ img+229376
//   Wlimg [1][64][320] @ img+331776
//   Wgcimg[1][64][128] @ img+352256
// Image storage: source k-chunk c (8 bf16) stored at chunk position c^(col&7)
// (XOR involution, matches the Bsh read formula ((ko>>3)^(col&7))<<3).

// ---------------------------------------------------------------------------
// K0: Wrels[r][f][h] = sum_nb comp[r][nb]*basis[nb][f][h]  (r<8); Wrels[8]=root
// ---------------------------------------------------------------------------
__global__ __launch_bounds__(256) void wrels_k(
    const float* __restrict__ basis, const float* __restrict__ comp,
    const float* __restrict__ root, float* __restrict__ wrels)
{
  int idx = blockIdx.x * 256 + threadIdx.x;        // 9*12800 = 115200
  if (idx >= 115200) return;
  int r = idx / 12800, fh = idx % 12800;
  float v;
  if (r < 8) {
    v = 0.f;
    #pragma unroll
    for (int nb = 0; nb < 30; ++nb) v += comp[r*30 + nb] * basis[nb*12800 + fh];
  } else {
    v = root[fh];
  }
  wrels[idx] = v;
}

// ---------------------------------------------------------------------------
// prep_k: (a) pack f32 modalities -> Ain[N][320] bf16 (cols 300..319 zero);
// (b) build all bf16 pre-swizzled weight tile images. Grid-stride, streaming.
// ---------------------------------------------------------------------------
__global__ __launch_bounds__(256) void prep_k(
    const float* __restrict__ textf, const float* __restrict__ acouf,
    const float* __restrict__ visuf, const float* __restrict__ wrels,
    const float* __restrict__ Wf, const float* __restrict__ Wma,
    const float* __restrict__ Wl, const float* __restrict__ Wrel,
    const float* __restrict__ Wroot2, __bf16* __restrict__ Ain,
    __bf16* __restrict__ img)
{
  constexpr int T0 = 1126400;            // Ain chunks: N*40
  constexpr int T1 = T0 + 10240;         // Wf   4*64*40
  constexpr int T2 = T1 + 18432;         // wrels 9*64*32
  constexpr int T3 = T2 + 12800;         // Wma  5*64*40
  constexpr int T4 = T3 + 2560;          // Wl   64*40
  constexpr int T5 = T4 + 1024;          // Wgc  64*16
  for (int c = blockIdx.x * 256 + threadIdx.x; c < T5; c += gridDim.x * 256) {
    bf16x8 v;
    __bf16* dst;
    if (c < T0) {
      const int m = c / 40, cc = c - m * 40;
      const int col0 = cc << 3;
      const size_t ab = (size_t)m * 100;
      #pragma unroll
      for (int e = 0; e < 8; ++e) {
        const int col = col0 + e;
        float x = (col < 100) ? textf[ab + col]
                : (col < 200) ? acouf[ab + col - 100]
                : (col < 300) ? visuf[ab + col - 200] : 0.f;
        v[e] = (__bf16)x;
      }
      dst = Ain + (size_t)m * 320 + col0;
    } else if (c < T1) {
      const int r = c - T0;
      const int cb = r / 2560, r2 = r - cb * 2560;
      const int col = r2 / 40, ch = r2 - col * 40;
      const int cs = (ch & ~7) | ((ch ^ col) & 7);
      const int gc = (cb << 6) + col;
      #pragma unroll
      for (int e = 0; e < 8; ++e) {
        const int k = (cs << 3) + e;
        v[e] = (__bf16)((k < 300 && gc < 200) ? Wf[k*200 + gc] : 0.f);
      }
      dst = img + cb * 20480 + col * 320 + (ch << 3);
    } else if (c < T2) {
      const int r = c - T1;
      const int cb = r / 2048, r2 = r - cb * 2048;
      const int col = r2 / 32, ch = r2 - col * 32;
      const int cs = (ch & ~7) | ((ch ^ col) & 7);
      #pragma unroll
      for (int e = 0; e < 8; ++e) {
        const int k = (cs << 3) + e;
        v[e] = (__bf16)((k < 200) ? wrels[cb*12800 + k*64 + col] : 0.f);
      }
      dst = img + 81920 + cb * 16384 + col * 256 + (ch << 3);
    } else if (c < T3) {
      const int r = c - T2;
      const int cb = r / 2560, r2 = r - cb * 2560;
      const int col = r2 / 40, ch = r2 - col * 40;
      const int cs = (ch & ~7) | ((ch ^ col) & 7);
      const int gc = (cb << 6) + col;
      #pragma unroll
      for (int e = 0; e < 8; ++e) {
        const int k = (cs << 3) + e;
        v[e] = (__bf16)((k < 264 && gc < 264) ? Wma[k*264 + gc] : 0.f);
      }
      dst = img + 229376 + cb * 20480 + col * 320 + (ch << 3);
    } else if (c < T4) {
      const int r = c - T3;
      const int col = r / 40, ch = r - col * 40;
      const int cs = (ch & ~7) | ((ch ^ col) & 7);
      #pragma unroll
      for (int e = 0; e < 8; ++e) {
        const int k = (cs << 3) + e;
        v[e] = (__bf16)((k < 264) ? Wl[k*64 + col] : 0.f);
      }
      dst = img + 331776 + col * 320 + (ch << 3);
    } else {
      const int r = c - T4;
      const int col = r / 16, ch = r - col * 16;
      const int cs = (ch & ~7) | ((ch ^ col) & 7);
      #pragma unroll
      for (int e = 0; e < 8; ++e) {
        const int k = (cs << 3) + e;
        v[e] = (__bf16)((k < 64) ? Wrel[k*64 + col] : Wroot2[(k-64)*64 + col]);
      }
      dst = img + 352256 + col * 128 + (ch << 3);
    }
    *(bf16x8*)dst = v;
  }
}

// ---------------------------------------------------------------------------
// bgemm: B-resident MFMA GEMM, bf16 A + pre-swizzled B image.
// Block = 64 rows x 64 cols, 256 thr = 4 waves (2M x 2N), wave tile 32x32.
// B-stage = linear 16B vector copy of the image tile (10 insts/thread max);
// A fragments straight from global bf16 (16B/lane). One barrier per block.
// MODE 0: A=Ain[N][320]. MODE 1: A=xb[N][200]. MODE 2: A=[xb|h2] split@200.
// OUT 1: bf16 stride Ncols. OUT 2: bf16 hi+lo planes, stride 288.
// ---------------------------------------------------------------------------
template<int MODE, int NK, int KSP, int NCB, int OUT>
__global__ __launch_bounds__(256) void bgemm_k(
    const __bf16* __restrict__ A0, const __bf16* __restrict__ A1,
    const __bf16* __restrict__ Bimg, const float* __restrict__ bias,
    void* __restrict__ Cv, int Ncols)
{
  __shared__ __align__(16) __bf16 Bsh[64][KSP];
  const int tid = threadIdx.x;
  constexpr int NWT = 440 * NCB;
  constexpr int q = NWT >> 3;
  const int bid = blockIdx.x;
  const int w = (bid & 7) * q + (bid >> 3);          // bijective XCD swizzle
  const int m0 = (w / NCB) << 6;
  const int cb = w % NCB;
  const int n0 = cb << 6;

  { // ---- B tile: linear vector copy of pre-swizzled image ----
    const bf16x8* src = (const bf16x8*)(Bimg + (size_t)cb * (64 * KSP));
    bf16x8* dst = (bf16x8*)&Bsh[0][0];
    constexpr int NIT = (64 * KSP / 8) / 256;
    #pragma unroll
    for (int c = 0; c < NIT; ++c) dst[c * 256 + tid] = src[c * 256 + tid];
  }
  __syncthreads();

  const int wid = tid >> 6, lane = tid & 63;
  const int wm = wid >> 1, wn = wid & 1;
  const int fr = lane & 15;
  const int fk = (lane >> 4) << 3;
  const int row0 = (lane >> 4) << 2;

  f32x4 acc[2][2];
  #pragma unroll
  for (int f = 0; f < 2; ++f)
    #pragma unroll
    for (int g = 0; g < 2; ++g) acc[f][g] = (f32x4){0.f,0.f,0.f,0.f};

  #pragma unroll
  for (int kt = 0; kt < NK; ++kt) {
    const int ko = (kt << 5) + fk;
    bf16x8 af[2];
    #pragma unroll
    for (int f = 0; f < 2; ++f) {
      const int ra = m0 + wm*32 + f*16 + fr;
      if constexpr (MODE == 2) {
        af[f] = (ko < 200) ? *(const bf16x8*)(A0 + (size_t)ra*200 + ko)
                           : *(const bf16x8*)(A1 + (size_t)ra*64 + (ko - 200));
      } else {
        constexpr int SA = (MODE == 0) ? 320 : 200;
        af[f] = *(const bf16x8*)(A0 + (size_t)ra*SA + ko);
      }
    }
    bf16x8 bfv[2];
    #pragma unroll
    for (int g = 0; g < 2; ++g) {
      const int rb_ = wn*32 + g*16 + fr;
      bfv[g] = *(const bf16x8*)&Bsh[rb_][(((ko >> 3) ^ (rb_ & 7)) << 3)];
    }
    #pragma unroll
    for (int f = 0; f < 2; ++f)
      #pragma unroll
      for (int g = 0; g < 2; ++g)
        acc[f][g] = __builtin_amdgcn_mfma_f32_16x16x32_bf16(af[f], bfv[g], acc[f][g], 0, 0, 0);
  }

  // ---- epilogue: D col=lane&15, row=(lane>>4)*4+reg ----
  #pragma unroll
  for (int g = 0; g < 2; ++g) {
    const int col = n0 + wn*32 + g*16 + fr;
    if (col < Ncols) {
      const float bv = bias ? bias[col] : 0.f;
      #pragma unroll
      for (int f = 0; f < 2; ++f) {
        const int gm0 = m0 + wm*32 + f*16 + row0;
        #pragma unroll
        for (int r2 = 0; r2 < 4; ++r2) {
          const float v = acc[f][g][r2] + bv;
          const int gm = gm0 + r2;
          if constexpr (OUT == 1) {
            ((__bf16*)Cv)[(size_t)gm * Ncols + col] = (__bf16)v;
          } else {
            __bf16* Cb = (__bf16*)Cv;
            const size_t o = (size_t)gm * 288 + col;
            const __bf16 hi = (__bf16)v;
            Cb[o] = hi;
            Cb[(size_t)288 * NND + o] = (__bf16)(v - (float)hi);
          }
        }
      }
    }
  }
}

// ---------------------------------------------------------------------------
// dialog_k: fused RGCN mean-agg + window-sum + GraphConv GEMM per dialogue.
// xr window slices bulk-staged to LDS (r9); [Wrel;Wroot2] from image.
// ---------------------------------------------------------------------------
__global__ __launch_bounds__(512) void dialog_k(
    const __bf16* __restrict__ xr, const int* __restrict__ spk,
    const float* __restrict__ brg, const __bf16* __restrict__ Wgcimg,
    const float* __restrict__ brel, __bf16* __restrict__ h2)
{
  __shared__ __align__(16) __bf16 Xsh[TT][320];
  __shared__ float h1f [TT][68];
  __shared__ float aggf[TT][68];
  __shared__ __align__(16) __bf16 Bsh[64][128];
  __shared__ int ssp[TT];
  const int b = blockIdx.x;
  const int tid = threadIdx.x;
  if (tid < TT) ssp[tid] = spk[tid * BBD + b];
  { // [Wrel;Wroot2] image copy: 1024 chunks, 512 thr
    const bf16x8* src = (const bf16x8*)Wgcimg;
    bf16x8* dst = (bf16x8*)&Bsh[0][0];
    dst[tid] = src[tid];
    dst[tid + 512] = src[tid + 512];
  }
  __syncthreads();      // ssp ready (needed for Xsh source addressing)
  // ---- stage xr slices: per j, 256 relation cols (s0-selected) + 64 root ----
  for (int i = tid << 3; i < TT * 320; i += 512 << 3) {
    const int j = i / 320, off = i - j * 320;
    const size_t base = ((size_t)j * BBD + b) * 576;
    const int col = (off < 256) ? ((ssp[j] << 8) + off) : (256 + off);
    *(bf16x8*)&Xsh[j][off] = *(const bf16x8*)&xr[base + col];
  }
  __syncthreads();
  const int w8 = tid >> 6, lane = tid & 63;
  const float bias = brg[lane];
  // ---- phase 1: h1 (reads LDS only) ----
  for (int t = w8; t < TT; t += 8) {
    const int si2 = ssp[t] << 1;
    const int jlo = imax(t - WIN, 0), jhi = imin(t + WIN, TT - 1);
    float a00=0.f, a01=0.f, a10=0.f, a11=0.f;
    int c00=0, c01=0, c10=0, c11=0;
    for (int j = jlo; j <= jhi; ++j) {
      const int s0 = ssp[j];
      const int dir = (j >= t) ? 1 : 0;
      const float v = (float)Xsh[j][((si2 + dir) << 6) + lane];
      if (s0) { if (dir) { a11 += v; ++c11; } else { a10 += v; ++c10; } }
      else    { if (dir) { a01 += v; ++c01; } else { a00 += v; ++c00; } }
    }
    float res = a00 / (float)imax(c00,1) + a01 / (float)imax(c01,1)
              + a10 / (float)imax(c10,1) + a11 / (float)imax(c11,1);
    res += (float)Xsh[t][256 + lane] + bias;
    h1f[t][lane] = res;
  }
  __syncthreads();
  // ---- phase 2: agg = window-sum(h1) ----
  for (int t = w8; t < TT; t += 8) {
    const int jlo = imax(t - WIN, 0), jhi = imin(t + WIN, TT - 1);
    float a = 0.f;
    for (int j = jlo; j <= jhi; ++j) a += h1f[j][lane];
    aggf[t][lane] = a;
  }
  __syncthreads();
  // ---- phase 3: h2 = [agg|h1] @ [Wrel;Wroot2] + brel ----
  const int wm = w8 >> 1, wn = w8 & 1;
  const int fr = lane & 15, fk = (lane >> 4) << 3, row0 = (lane >> 4) << 2;
  f32x4 acc[2][2];
  #pragma unroll
  for (int f = 0; f < 2; ++f)
    #pragma unroll
    for (int g = 0; g < 2; ++g) acc[f][g] = (f32x4){0.f,0.f,0.f,0.f};
  #pragma unroll
  for (int kt = 0; kt < 4; ++kt) {
    const int ko = (kt << 5) + fk;
    bf16x8 af[2];
    #pragma unroll
    for (int f = 0; f < 2; ++f) {
      const int tr = wm*32 + f*16 + fr;
      if (tr < TT) {
        const float* src = (ko < 64) ? &aggf[tr][ko] : &h1f[tr][ko - 64];
        const float4 u0 = ((const float4*)src)[0];
        const float4 u1 = ((const float4*)src)[1];
        af[f] = (bf16x8){(__bf16)u0.x,(__bf16)u0.y,(__bf16)u0.z,(__bf16)u0.w,
                         (__bf16)u1.x,(__bf16)u1.y,(__bf16)u1.z,(__bf16)u1.w};
      } else af[f] = (bf16x8){0,0,0,0,0,0,0,0};
    }
    bf16x8 bfv[2];
    #pragma unroll
    for (int g = 0; g < 2; ++g) {
      const int rb_ = wn*32 + g*16 + fr;
      bfv[g] = *(const bf16x8*)&Bsh[rb_][(((ko >> 3) ^ (rb_ & 7)) << 3)];
    }
    #pragma unroll
    for (int f = 0; f < 2; ++f)
      #pragma unroll
      for (int g = 0; g < 2; ++g)
        acc[f][g] = __builtin_amdgcn_mfma_f32_16x16x32_bf16(af[f], bfv[g], acc[f][g], 0, 0, 0);
  }
  #pragma unroll
  for (int g = 0; g < 2; ++g) {
    const int col = wn*32 + g*16 + fr;
    const float bv = brel[col];
    #pragma unroll
    for (int f = 0; f < 2; ++f) {
      const int t0_ = wm*32 + f*16 + row0;
      #pragma unroll
      for (int r2 = 0; r2 < 4; ++r2) {
        const int t = t0_ + r2;
        if (t < TT) h2[((size_t)t * BBD + b) * 64 + col] = (__bf16)(acc[f][g][r2] + bv);
      }
    }
  }
}

// ---------------------------------------------------------------------------
// attn: MFMA matching attention, one block (448 thr = 7 waves) per dialogue.
// ---------------------------------------------------------------------------
__global__ __launch_bounds__(448) void attn_mfma_k(
    const __bf16* __restrict__ x, const __bf16* __restrict__ h2,
    const __bf16* __restrict__ Xq, __bf16* __restrict__ att)
{
  __shared__ __align__(16) __bf16 Msh [TT ][272];
  __shared__ __align__(16) __bf16 MTsh[264][136];
  __shared__ __align__(16) __bf16 Ash [112][136];
  const int b = blockIdx.x;
  const int tid = threadIdx.x;

  for (int idx = tid; idx < TT * 66; idx += 448) {
    const int s = idx / 66, c4 = idx % 66;
    const size_t node = (size_t)s * BBD + b;
    bf16x4 pk;
    if (c4 < 50) pk = *(const bf16x4*)&x [node * 200 + (c4 << 2)];
    else         pk = *(const bf16x4*)&h2[node * 64 + ((c4 - 50) << 2)];
    *(bf16x4*)&Msh[s][c4 << 2] = pk;
    const int d = c4 << 2;
    MTsh[d+0][s] = pk[0]; MTsh[d+1][s] = pk[1];
    MTsh[d+2][s] = pk[2]; MTsh[d+3][s] = pk[3];
  }
  for (int idx = tid; idx < 264 * 26; idx += 448) MTsh[idx / 26][110 + idx % 26] = (__bf16)0.f;
  for (int idx = tid; idx < 112 * 24; idx += 448) Ash[idx / 24][112 + idx % 24] = (__bf16)0.f;
  __syncthreads();

  const int wid = tid >> 6, lane = tid & 63;
  const int t0 = wid << 4;
  const int fr = lane & 15;
  const int g  = lane >> 4;
  const int fk = g << 3;

  f32x4 sacc[7];
  #pragma unroll
  for (int st = 0; st < 7; ++st) sacc[st] = (f32x4){0.f,0.f,0.f,0.f};
  const int trow = t0 + fr;
  const size_t arow = ((size_t)(trow < TT ? trow : TT - 1) * BBD + b) * 288;
  const __bf16* XqLo = Xq + (size_t)288 * NND;
  for (int kst = 0; kst < 9; ++kst) {
    const int k0 = kst << 5;
    bf16x8 aqh = *(const bf16x8*)&Xq  [arow + k0 + fk];
    bf16x8 aql = *(const bf16x8*)&XqLo[arow + k0 + fk];
    if (kst == 8 && fk != 0) {
      aqh = (bf16x8){0,0,0,0,0,0,0,0};
      aql = (bf16x8){0,0,0,0,0,0,0,0};
    }
    #pragma unroll
    for (int st = 0; st < 7; ++st) {
      bf16x8 bq;
      if (kst < 8) bq = *(const bf16x8*)&Msh[st*16 + fr][k0 + fk];
      else bq = (fk == 0) ? *(const bf16x8*)&Msh[st*16 + fr][256]
                          : (bf16x8){0,0,0,0,0,0,0,0};
      sacc[st] = __builtin_amdgcn_mfma_f32_16x16x32_bf16(aqh, bq, sacc[st], 0, 0, 0);
      sacc[st] = __builtin_amdgcn_mfma_f32_16x16x32_bf16(aql, bq, sacc[st], 0, 0, 0);
    }
  }

  #pragma unroll
  for (int r = 0; r < 4; ++r) {
    float tv[7];
    #pragma unroll
    for (int st = 0; st < 7; ++st) {
      const float e2 = __expf(2.f * sacc[st][r]);
      tv[st] = 1.f - 2.f / (e2 + 1.f);
    }
    if (fr >= 14) tv[6] = -3.0e38f;
    float mx = fmaxf(fmaxf(fmaxf(tv[0],tv[1]), fmaxf(tv[2],tv[3])),
                     fmaxf(fmaxf(tv[4],tv[5]), tv[6]));
    #pragma unroll
    for (int o = 8; o >= 1; o >>= 1) mx = fmaxf(mx, __shfl_xor(mx, o, 16));
    float e[7], sum = 0.f;
    #pragma unroll
    for (int st = 0; st < 7; ++st) { e[st] = __expf(tv[st] - mx); sum += e[st]; }
    #pragma unroll
    for (int o = 8; o >= 1; o >>= 1) sum += __shfl_xor(sum, o, 16);
    const float inv = 1.f / sum;
    const int tr = t0 + (g << 2) + r;
    #pragma unroll
    for (int st = 0; st < 7; ++st) Ash[tr][st*16 + fr] = (__bf16)(e[st] * inv);
  }
  __syncthreads();

  const int tr2 = t0 + (g << 2);
  for (int dt = 0; dt < 17; ++dt) {
    const int d0 = dt << 4;
    f32x4 pacc = (f32x4){0.f,0.f,0.f,0.f};
    #pragma unroll
    for (int kst = 0; kst < 4; ++kst) {
      const int k0 = kst << 5;
      const bf16x8 pa = *(const bf16x8*)&Ash [t0 + fr][k0 + fk];
      const bf16x8 pb = *(const bf16x8*)&MTsh[d0 + fr][k0 + fk];
      pacc = __builtin_amdgcn_mfma_f32_16x16x32_bf16(pa, pb, pacc, 0, 0, 0);
    }
    const int col = d0 + fr;
    if (col < 264) {
      #pragma unroll
      for (int r = 0; r < 4; ++r) {
        const int t = tr2 + r;
        if (t < TT) att[((size_t)t * BBD + b) * 264 + col] = (__bf16)pacc[r];
      }
    }
  }
}

// ---------------------------------------------------------------------------
// final_k: fused hidden GEMM (att@Wl+bl, ReLU) + logits + log_softmax.
// Wl from pre-swizzled image (vector copy).
// ---------------------------------------------------------------------------
__global__ __launch_bounds__(256) void final_k(
    const __bf16* __restrict__ att, const __bf16* __restrict__ Wlimg,
    const float* __restrict__ bl, const float* __restrict__ Wsm,
    const float* __restrict__ bsm, float* __restrict__ out)
{
  constexpr int KSP = 320;
  __shared__ __align__(16) __bf16 Bsh[64][KSP];
  __shared__ float hidf[64][68];
  __shared__ float Wssh[64][8];
  const int tid = threadIdx.x;
  const int bid = blockIdx.x;
  const int m0 = ((bid & 7) * 55 + (bid >> 3)) << 6;   // 440 = 8*55
  {
    const bf16x8* src = (const bf16x8*)Wlimg;
    bf16x8* dst = (bf16x8*)&Bsh[0][0];
    #pragma unroll
    for (int c = 0; c < 10; ++c) dst[c * 256 + tid] = src[c * 256 + tid];
    for (int i = tid; i < 512; i += 256) {
      const int k = i >> 3, cc = i & 7;
      Wssh[k][cc] = (cc < 7) ? Wsm[k*7 + cc] : 0.f;
    }
  }
  __syncthreads();
  const int wid = tid >> 6, lane = tid & 63;
  const int wm = wid >> 1, wn = wid & 1;
  const int fr = lane & 15, fk = (lane >> 4) << 3, row0 = (lane >> 4) << 2;
  f32x4 acc[2][2];
  #pragma unroll
  for (int f = 0; f < 2; ++f)
    #pragma unroll
    for (int g = 0; g < 2; ++g) acc[f][g] = (f32x4){0.f,0.f,0.f,0.f};
  #pragma unroll
  for (int kt = 0; kt < 9; ++kt) {
    const int ko = (kt << 5) + fk;
    bf16x8 af[2];
    #pragma unroll
    for (int f = 0; f < 2; ++f) {
      const int ra = m0 + wm*32 + f*16 + fr;
      af[f] = (ko < 264) ? *(const bf16x8*)(att + (size_t)ra*264 + ko)
                         : (bf16x8){0,0,0,0,0,0,0,0};
    }
    bf16x8 bfv[2];
    #pragma unroll
    for (int g = 0; g < 2; ++g) {
      const int rb_ = wn*32 + g*16 + fr;
      bfv[g] = *(const bf16x8*)&Bsh[rb_][(((ko >> 3) ^ (rb_ & 7)) << 3)];
    }
    #pragma unroll
    for (int f = 0; f < 2; ++f)
      #pragma unroll
      for (int g = 0; g < 2; ++g)
        acc[f][g] = __builtin_amdgcn_mfma_f32_16x16x32_bf16(af[f], bfv[g], acc[f][g], 0, 0, 0);
  }
  // hidden tile -> LDS (ReLU + bias)
  #pragma unroll
  for (int g = 0; g < 2; ++g) {
    const int col = wn*32 + g*16 + fr;
    const float bv = bl[col];
    #pragma unroll
    for (int f = 0; f < 2; ++f) {
      const int lr0 = wm*32 + f*16 + row0;
      #pragma unroll
      for (int r2 = 0; r2 < 4; ++r2)
        hidf[lr0 + r2][col] = fmaxf(acc[f][g][r2] + bv, 0.f);
    }
  }
  __syncthreads();
  // logits + log_softmax: 2 passes of 32 rows, 8 lanes per row
  const int c = tid & 7;
  const float bc = (c < 7) ? bsm[c] : 0.f;
  #pragma unroll
  for (int p = 0; p < 2; ++p) {
    const int lr = (p << 5) + (tid >> 3);
    float lg = -3.0e38f;
    if (c < 7) {
      lg = bc;
      #pragma unroll
      for (int k = 0; k < 64; ++k) lg += hidf[lr][k] * Wssh[k][c];
    }
    float mx = lg;
    #pragma unroll
    for (int o = 4; o >= 1; o >>= 1) mx = fmaxf(mx, __shfl_xor(mx, o, 8));
    float e = (c < 7) ? __expf(lg - mx) : 0.f;
    float sm = e;
    #pragma unroll
    for (int o = 4; o >= 1; o >>= 1) sm += __shfl_xor(sm, o, 8);
    if (c < 7) {
      const int gm = m0 + lr;                 // gm = t*256 + b
      const int t = gm >> 8, bb = gm & 255;
      out[((size_t)bb * TT + t) * 7 + c] = lg - mx - __logf(sm);
    }
  }
}

// ---------------------------------------------------------------------------
extern "C" void kernel_launch(void* const* d_in, const int* in_sizes, int n_in,
                              void* d_out, int out_size, void* d_ws, size_t ws_size,
                              hipStream_t stream)
{
  const float* textf  = (const float*)d_in[0];
  const float* acouf  = (const float*)d_in[1];
  const float* visuf  = (const float*)d_in[2];
  const int*   spk    = (const int*)  d_in[3];
  const float* Wf     = (const float*)d_in[4];
  const float* bfv    = (const float*)d_in[5];
  const float* basis  = (const float*)d_in[6];
  const float* comp   = (const float*)d_in[7];
  const float* root   = (const float*)d_in[8];
  const float* brg    = (const float*)d_in[9];
  const float* Wrel   = (const float*)d_in[10];
  const float* brel   = (const float*)d_in[11];
  const float* Wroot2 = (const float*)d_in[12];
  const float* Wma    = (const float*)d_in[13];
  const float* bma    = (const float*)d_in[14];
  const float* Wl     = (const float*)d_in[15];
  const float* bl     = (const float*)d_in[16];
  const float* Wsm    = (const float*)d_in[17];
  const float* bsm    = (const float*)d_in[18];

  float* ws = (float*)d_ws;
  float*  wrels = ws;                               // @0        (115,200 f32)
  __bf16* img   = (__bf16*)(ws + 115200);           // 360,448 bf16 images
  __bf16* Ain   = (__bf16*)(ws + 295424);           // N*320 bf16
  __bf16* xb    = (__bf16*)(ws + 4801024);          // N*200 bf16
  __bf16* xr    = (__bf16*)(ws + 7617024);          // N*576 bf16 (att aliases)
  __bf16* h2    = (__bf16*)(ws + 15727104);         // N*64 bf16
  __bf16* Xqb   = (__bf16*)(ws + 16628224);         // 2*N*288 bf16
  __bf16* attb  = xr;                               // alias (dead after dialog_k)
  float*  outp  = (float*)d_out;

  __bf16* Wfimg  = img;
  __bf16* wrimg  = img + 81920;
  __bf16* Wmaimg = img + 229376;
  __bf16* Wlimg  = img + 331776;
  __bf16* Wgcimg = img + 352256;

  wrels_k<<<450, 256, 0, stream>>>(basis, comp, root, wrels);
  prep_k<<<2048, 256, 0, stream>>>(textf, acouf, visuf, wrels, Wf, Wma, Wl,
                                   Wrel, Wroot2, Ain, img);
  bgemm_k<0,10,320,4,1><<<1760, 256, 0, stream>>>(Ain, nullptr, Wfimg, bfv, xb, 200);
  bgemm_k<1,7,256,9,1><<<3960, 256, 0, stream>>>(xb, nullptr, wrimg, nullptr, xr, 576);
  dialog_k<<<256, 512, 0, stream>>>(xr, spk, brg, Wgcimg, brel, h2);
  bgemm_k<2,9,320,5,2><<<2200, 256, 0, stream>>>(xb, h2, Wmaimg, bma, Xqb, 264);
  attn_mfma_k<<<256, 448, 0, stream>>>(xb, h2, Xqb, attb);
  final_k<<<440, 256, 0, stream>>>(attb, Wlimg, bl, Wsm, bsm, outp);
}

// Round 11
// 181.803 us; speedup vs baseline: 2.6913x; 1.0398x over previous
//
#include <hip/hip_runtime.h>

#define TT   110          // max_seq_len
#define BBD  256          // num dialogues
#define NND  28160        // TT*BBD
#define WIN  10

typedef __bf16 bf16x8 __attribute__((ext_vector_type(8)));
typedef __bf16 bf16x4 __attribute__((ext_vector_type(4)));
typedef float  f32x4  __attribute__((ext_vector_type(4)));

__device__ __forceinline__ int imax(int a, int b){ return a > b ? a : b; }
__device__ __forceinline__ int imin(int a, int b){ return a < b ? a : b; }

// All per-node matrices are SOURCE-MAJOR: row m = t*256 + b  (node n = b*110+t).
// Weight images (bf16, pre-swizzled per 64-col tile, row=col, KSP elems):
//   Wfimg [4][64][320] @ img+0
//   wrimg [9][64][256] @ img+81920
//   Wmaimg[5][64][320] @ img+229376
//   Wlimg [1][64][320] @ img+331776
//   Wgcimg[1][64][128] @ img+352256
// Image storage: source k-chunk c (8 bf16) stored at chunk position c^(col&7)
// (XOR involution, matches the Bsh read formula ((ko>>3)^(col&7))<<3).

// ---------------------------------------------------------------------------
// K0: Wrels[r][f][h] = sum_nb comp[r][nb]*basis[nb][f][h]  (r<8); Wrels[8]=root
// ---------------------------------------------------------------------------
__global__ __launch_bounds__(256) void wrels_k(
    const float* __restrict__ basis, const float* __restrict__ comp,
    const float* __restrict__ root, float* __restrict__ wrels)
{
  int idx = blockIdx.x * 256 + threadIdx.x;        // 9*12800 = 115200
  if (idx >= 115200) return;
  int r = idx / 12800, fh = idx % 12800;
  float v;
  if (r < 8) {
    v = 0.f;
    #pragma unroll
    for (int nb = 0; nb < 30; ++nb) v += comp[r*30 + nb] * basis[nb*12800 + fh];
  } else {
    v = root[fh];
  }
  wrels[idx] = v;
}

// ---------------------------------------------------------------------------
// prep_k: (a) pack f32 modalities -> Ain[N][320] bf16 (cols 300..319 zero);
// (b) build all bf16 pre-swizzled weight tile images. Grid-stride, streaming.
// ---------------------------------------------------------------------------
__global__ __launch_bounds__(256) void prep_k(
    const float* __restrict__ textf, const float* __restrict__ acouf,
    const float* __restrict__ visuf, const float* __restrict__ wrels,
    const float* __restrict__ Wf, const float* __restrict__ Wma,
    const float* __restrict__ Wl, const float* __restrict__ Wrel,
    const float* __restrict__ Wroot2, __bf16* __restrict__ Ain,
    __bf16* __restrict__ img)
{
  constexpr int T0 = 1126400;            // Ain chunks: N*40
  constexpr int T1 = T0 + 10240;         // Wf   4*64*40
  constexpr int T2 = T1 + 18432;         // wrels 9*64*32
  constexpr int T3 = T2 + 12800;         // Wma  5*64*40
  constexpr int T4 = T3 + 2560;          // Wl   64*40
  constexpr int T5 = T4 + 1024;          // Wgc  64*16
  for (int c = blockIdx.x * 256 + threadIdx.x; c < T5; c += gridDim.x * 256) {
    bf16x8 v;
    __bf16* dst;
    if (c < T0) {
      const int m = c / 40, cc = c - m * 40;
      const int col0 = cc << 3;
      const size_t ab = (size_t)m * 100;
      #pragma unroll
      for (int e = 0; e < 8; ++e) {
        const int col = col0 + e;
        float x = (col < 100) ? textf[ab + col]
                : (col < 200) ? acouf[ab + col - 100]
                : (col < 300) ? visuf[ab + col - 200] : 0.f;
        v[e] = (__bf16)x;
      }
      dst = Ain + (size_t)m * 320 + col0;
    } else if (c < T1) {
      const int r = c - T0;
      const int cb = r / 2560, r2 = r - cb * 2560;
      const int col = r2 / 40, ch = r2 - col * 40;
      const int cs = (ch & ~7) | ((ch ^ col) & 7);
      const int gc = (cb << 6) + col;
      #pragma unroll
      for (int e = 0; e < 8; ++e) {
        const int k = (cs << 3) + e;
        v[e] = (__bf16)((k < 300 && gc < 200) ? Wf[k*200 + gc] : 0.f);
      }
      dst = img + cb * 20480 + col * 320 + (ch << 3);
    } else if (c < T2) {
      const int r = c - T1;
      const int cb = r / 2048, r2 = r - cb * 2048;
      const int col = r2 / 32, ch = r2 - col * 32;
      const int cs = (ch & ~7) | ((ch ^ col) & 7);
      #pragma unroll
      for (int e = 0; e < 8; ++e) {
        const int k = (cs << 3) + e;
        v[e] = (__bf16)((k < 200) ? wrels[cb*12800 + k*64 + col] : 0.f);
      }
      dst = img + 81920 + cb * 16384 + col * 256 + (ch << 3);
    } else if (c < T3) {
      const int r = c - T2;
      const int cb = r / 2560, r2 = r - cb * 2560;
      const int col = r2 / 40, ch = r2 - col * 40;
      const int cs = (ch & ~7) | ((ch ^ col) & 7);
      const int gc = (cb << 6) + col;
      #pragma unroll
      for (int e = 0; e < 8; ++e) {
        const int k = (cs << 3) + e;
        v[e] = (__bf16)((k < 264 && gc < 264) ? Wma[k*264 + gc] : 0.f);
      }
      dst = img + 229376 + cb * 20480 + col * 320 + (ch << 3);
    } else if (c < T4) {
      const int r = c - T3;
      const int col = r / 40, ch = r - col * 40;
      const int cs = (ch & ~7) | ((ch ^ col) & 7);
      #pragma unroll
      for (int e = 0; e < 8; ++e) {
        const int k = (cs << 3) + e;
        v[e] = (__bf16)((k < 264) ? Wl[k*64 + col] : 0.f);
      }
      dst = img + 331776 + col * 320 + (ch << 3);
    } else {
      const int r = c - T4;
      const int col = r / 16, ch = r - col * 16;
      const int cs = (ch & ~7) | ((ch ^ col) & 7);
      #pragma unroll
      for (int e = 0; e < 8; ++e) {
        const int k = (cs << 3) + e;
        v[e] = (__bf16)((k < 64) ? Wrel[k*64 + col] : Wroot2[(k-64)*64 + col]);
      }
      dst = img + 352256 + col * 128 + (ch << 3);
    }
    *(bf16x8*)dst = v;
  }
}

// ---------------------------------------------------------------------------
// bgemm: B-resident MFMA GEMM, bf16 A + pre-swizzled B image.
// ---------------------------------------------------------------------------
template<int MODE, int NK, int KSP, int NCB, int OUT>
__global__ __launch_bounds__(256) void bgemm_k(
    const __bf16* __restrict__ A0, const __bf16* __restrict__ A1,
    const __bf16* __restrict__ Bimg, const float* __restrict__ bias,
    void* __restrict__ Cv, int Ncols)
{
  __shared__ __align__(16) __bf16 Bsh[64][KSP];
  const int tid = threadIdx.x;
  constexpr int NWT = 440 * NCB;
  constexpr int q = NWT >> 3;
  const int bid = blockIdx.x;
  const int w = (bid & 7) * q + (bid >> 3);          // bijective XCD swizzle
  const int m0 = (w / NCB) << 6;
  const int cb = w % NCB;
  const int n0 = cb << 6;

  { // ---- B tile: linear vector copy of pre-swizzled image ----
    const bf16x8* src = (const bf16x8*)(Bimg + (size_t)cb * (64 * KSP));
    bf16x8* dst = (bf16x8*)&Bsh[0][0];
    constexpr int NIT = (64 * KSP / 8) / 256;
    #pragma unroll
    for (int c = 0; c < NIT; ++c) dst[c * 256 + tid] = src[c * 256 + tid];
  }
  __syncthreads();

  const int wid = tid >> 6, lane = tid & 63;
  const int wm = wid >> 1, wn = wid & 1;
  const int fr = lane & 15;
  const int fk = (lane >> 4) << 3;
  const int row0 = (lane >> 4) << 2;

  f32x4 acc[2][2];
  #pragma unroll
  for (int f = 0; f < 2; ++f)
    #pragma unroll
    for (int g = 0; g < 2; ++g) acc[f][g] = (f32x4){0.f,0.f,0.f,0.f};

  #pragma unroll
  for (int kt = 0; kt < NK; ++kt) {
    const int ko = (kt << 5) + fk;
    bf16x8 af[2];
    #pragma unroll
    for (int f = 0; f < 2; ++f) {
      const int ra = m0 + wm*32 + f*16 + fr;
      if constexpr (MODE == 2) {
        af[f] = (ko < 200) ? *(const bf16x8*)(A0 + (size_t)ra*200 + ko)
                           : *(const bf16x8*)(A1 + (size_t)ra*64 + (ko - 200));
      } else {
        constexpr int SA = (MODE == 0) ? 320 : 200;
        af[f] = *(const bf16x8*)(A0 + (size_t)ra*SA + ko);
      }
    }
    bf16x8 bfv[2];
    #pragma unroll
    for (int g = 0; g < 2; ++g) {
      const int rb_ = wn*32 + g*16 + fr;
      bfv[g] = *(const bf16x8*)&Bsh[rb_][(((ko >> 3) ^ (rb_ & 7)) << 3)];
    }
    #pragma unroll
    for (int f = 0; f < 2; ++f)
      #pragma unroll
      for (int g = 0; g < 2; ++g)
        acc[f][g] = __builtin_amdgcn_mfma_f32_16x16x32_bf16(af[f], bfv[g], acc[f][g], 0, 0, 0);
  }

  // ---- epilogue: D col=lane&15, row=(lane>>4)*4+reg ----
  #pragma unroll
  for (int g = 0; g < 2; ++g) {
    const int col = n0 + wn*32 + g*16 + fr;
    if (col < Ncols) {
      const float bv = bias ? bias[col] : 0.f;
      #pragma unroll
      for (int f = 0; f < 2; ++f) {
        const int gm0 = m0 + wm*32 + f*16 + row0;
        #pragma unroll
        for (int r2 = 0; r2 < 4; ++r2) {
          const float v = acc[f][g][r2] + bv;
          const int gm = gm0 + r2;
          if constexpr (OUT == 1) {
            ((__bf16*)Cv)[(size_t)gm * Ncols + col] = (__bf16)v;
          } else {
            __bf16* Cb = (__bf16*)Cv;
            const size_t o = (size_t)gm * 288 + col;
            const __bf16 hi = (__bf16)v;
            Cb[o] = hi;
            Cb[(size_t)288 * NND + o] = (__bf16)(v - (float)hi);
          }
        }
      }
    }
  }
}

// ---------------------------------------------------------------------------
// dialog_k: fused RGCN mean-agg + window-sum + GraphConv GEMM per dialogue.
// ROUND 11: phases 1-2 fully unrolled over the +-10 window (compile-time taps
// -> all 21 ds_reads issue back-to-back); counts via speaker prefix-sum pc[].
// ---------------------------------------------------------------------------
__global__ __launch_bounds__(512) void dialog_k(
    const __bf16* __restrict__ xr, const int* __restrict__ spk,
    const float* __restrict__ brg, const __bf16* __restrict__ Wgcimg,
    const float* __restrict__ brel, __bf16* __restrict__ h2)
{
  __shared__ __align__(16) __bf16 Xsh[TT][320];
  __shared__ float h1f [TT][68];
  __shared__ float aggf[TT][68];
  __shared__ __align__(16) __bf16 Bsh[64][128];
  __shared__ int ssp[TT];
  __shared__ int pc[TT + 1];
  const int b = blockIdx.x;
  const int tid = threadIdx.x;
  if (tid < TT) ssp[tid] = spk[tid * BBD + b];
  { // [Wrel;Wroot2] image copy: 1024 chunks, 512 thr
    const bf16x8* src = (const bf16x8*)Wgcimg;
    bf16x8* dst = (bf16x8*)&Bsh[0][0];
    dst[tid] = src[tid];
    dst[tid + 512] = src[tid + 512];
  }
  __syncthreads();      // ssp ready
  // ---- stage xr slices (bulk); one thread builds the speaker prefix sum ----
  if (tid == 511) {
    int s = 0;
    pc[0] = 0;
    for (int j = 0; j < TT; ++j) { s += ssp[j]; pc[j + 1] = s; }
  }
  for (int i = tid << 3; i < TT * 320; i += 512 << 3) {
    const int j = i / 320, off = i - j * 320;
    const size_t base = ((size_t)j * BBD + b) * 576;
    const int col = (off < 256) ? ((ssp[j] << 8) + off) : (256 + off);
    *(bf16x8*)&Xsh[j][off] = *(const bf16x8*)&xr[base + col];
  }
  __syncthreads();
  const int w8 = tid >> 6, lane = tid & 63;
  const float bias = brg[lane];
  // ---- phase 1: h1 (unrolled window, LDS reads only) ----
  for (int t = w8; t < TT; t += 8) {
    const int si2 = ssp[t] << 1;
    float a00 = 0.f, a01 = 0.f, a10 = 0.f, a11 = 0.f;
    #pragma unroll
    for (int dj = -WIN; dj <= WIN; ++dj) {
      const int j = t + dj;
      const int jc = imin(imax(j, 0), TT - 1);
      const int cdir = (dj >= 0) ? 1 : 0;                 // compile-time
      const float v = (float)Xsh[jc][((si2 + cdir) << 6) + lane];
      const bool ok = (j >= 0) && (j < TT);               // wave-uniform
      const float m1 = (ok && ssp[jc] != 0) ? 1.f : 0.f;  // scalar selects
      const float m0 = (ok && ssp[jc] == 0) ? 1.f : 0.f;
      if (dj >= 0) { a01 = fmaf(m0, v, a01); a11 = fmaf(m1, v, a11); }
      else         { a00 = fmaf(m0, v, a00); a10 = fmaf(m1, v, a10); }
    }
    const int jlo = imax(t - WIN, 0), jhi = imin(t + WIN, TT - 1);
    const int n1d0 = pc[t] - pc[jlo];
    const int n0d0 = (t - jlo) - n1d0;
    const int n1d1 = pc[jhi + 1] - pc[t];
    const int n0d1 = (jhi - t + 1) - n1d1;
    float res = a00 / (float)imax(n0d0, 1) + a01 / (float)imax(n0d1, 1)
              + a10 / (float)imax(n1d0, 1) + a11 / (float)imax(n1d1, 1);
    res += (float)Xsh[t][256 + lane] + bias;
    h1f[t][lane] = res;
  }
  __syncthreads();
  // ---- phase 2: agg = window-sum(h1), unrolled ----
  for (int t = w8; t < TT; t += 8) {
    float a = 0.f;
    #pragma unroll
    for (int dj = -WIN; dj <= WIN; ++dj) {
      const int j = t + dj;
      const int jc = imin(imax(j, 0), TT - 1);
      const float m = ((j >= 0) && (j < TT)) ? 1.f : 0.f;
      a = fmaf(m, h1f[jc][lane], a);
    }
    aggf[t][lane] = a;
  }
  __syncthreads();
  // ---- phase 3: h2 = [agg|h1] @ [Wrel;Wroot2] + brel ----
  const int wm = w8 >> 1, wn = w8 & 1;
  const int fr = lane & 15, fk = (lane >> 4) << 3, row0 = (lane >> 4) << 2;
  f32x4 acc[2][2];
  #pragma unroll
  for (int f = 0; f < 2; ++f)
    #pragma unroll
    for (int g = 0; g < 2; ++g) acc[f][g] = (f32x4){0.f,0.f,0.f,0.f};
  #pragma unroll
  for (int kt = 0; kt < 4; ++kt) {
    const int ko = (kt << 5) + fk;
    bf16x8 af[2];
    #pragma unroll
    for (int f = 0; f < 2; ++f) {
      const int tr = wm*32 + f*16 + fr;
      if (tr < TT) {
        const float* src = (ko < 64) ? &aggf[tr][ko] : &h1f[tr][ko - 64];
        const float4 u0 = ((const float4*)src)[0];
        const float4 u1 = ((const float4*)src)[1];
        af[f] = (bf16x8){(__bf16)u0.x,(__bf16)u0.y,(__bf16)u0.z,(__bf16)u0.w,
                         (__bf16)u1.x,(__bf16)u1.y,(__bf16)u1.z,(__bf16)u1.w};
      } else af[f] = (bf16x8){0,0,0,0,0,0,0,0};
    }
    bf16x8 bfv[2];
    #pragma unroll
    for (int g = 0; g < 2; ++g) {
      const int rb_ = wn*32 + g*16 + fr;
      bfv[g] = *(const bf16x8*)&Bsh[rb_][(((ko >> 3) ^ (rb_ & 7)) << 3)];
    }
    #pragma unroll
    for (int f = 0; f < 2; ++f)
      #pragma unroll
      for (int g = 0; g < 2; ++g)
        acc[f][g] = __builtin_amdgcn_mfma_f32_16x16x32_bf16(af[f], bfv[g], acc[f][g], 0, 0, 0);
  }
  #pragma unroll
  for (int g = 0; g < 2; ++g) {
    const int col = wn*32 + g*16 + fr;
    const float bv = brel[col];
    #pragma unroll
    for (int f = 0; f < 2; ++f) {
      const int t0_ = wm*32 + f*16 + row0;
      #pragma unroll
      for (int r2 = 0; r2 < 4; ++r2) {
        const int t = t0_ + r2;
        if (t < TT) h2[((size_t)t * BBD + b) * 64 + col] = (__bf16)(acc[f][g][r2] + bv);
      }
    }
  }
}

// ---------------------------------------------------------------------------
// attn: MFMA matching attention, one block (448 thr = 7 waves) per dialogue.
// ---------------------------------------------------------------------------
__global__ __launch_bounds__(448) void attn_mfma_k(
    const __bf16* __restrict__ x, const __bf16* __restrict__ h2,
    const __bf16* __restrict__ Xq, __bf16* __restrict__ att)
{
  __shared__ __align__(16) __bf16 Msh [TT ][272];
  __shared__ __align__(16) __bf16 MTsh[264][136];
  __shared__ __align__(16) __bf16 Ash [112][136];
  const int b = blockIdx.x;
  const int tid = threadIdx.x;

  for (int idx = tid; idx < TT * 66; idx += 448) {
    const int s = idx / 66, c4 = idx % 66;
    const size_t node = (size_t)s * BBD + b;
    bf16x4 pk;
    if (c4 < 50) pk = *(const bf16x4*)&x [node * 200 + (c4 << 2)];
    else         pk = *(const bf16x4*)&h2[node * 64 + ((c4 - 50) << 2)];
    *(bf16x4*)&Msh[s][c4 << 2] = pk;
    const int d = c4 << 2;
    MTsh[d+0][s] = pk[0]; MTsh[d+1][s] = pk[1];
    MTsh[d+2][s] = pk[2]; MTsh[d+3][s] = pk[3];
  }
  for (int idx = tid; idx < 264 * 26; idx += 448) MTsh[idx / 26][110 + idx % 26] = (__bf16)0.f;
  for (int idx = tid; idx < 112 * 24; idx += 448) Ash[idx / 24][112 + idx % 24] = (__bf16)0.f;
  __syncthreads();

  const int wid = tid >> 6, lane = tid & 63;
  const int t0 = wid << 4;
  const int fr = lane & 15;
  const int g  = lane >> 4;
  const int fk = g << 3;

  f32x4 sacc[7];
  #pragma unroll
  for (int st = 0; st < 7; ++st) sacc[st] = (f32x4){0.f,0.f,0.f,0.f};
  const int trow = t0 + fr;
  const size_t arow = ((size_t)(trow < TT ? trow : TT - 1) * BBD + b) * 288;
  const __bf16* XqLo = Xq + (size_t)288 * NND;
  for (int kst = 0; kst < 9; ++kst) {
    const int k0 = kst << 5;
    bf16x8 aqh = *(const bf16x8*)&Xq  [arow + k0 + fk];
    bf16x8 aql = *(const bf16x8*)&XqLo[arow + k0 + fk];
    if (kst == 8 && fk != 0) {
      aqh = (bf16x8){0,0,0,0,0,0,0,0};
      aql = (bf16x8){0,0,0,0,0,0,0,0};
    }
    #pragma unroll
    for (int st = 0; st < 7; ++st) {
      bf16x8 bq;
      if (kst < 8) bq = *(const bf16x8*)&Msh[st*16 + fr][k0 + fk];
      else bq = (fk == 0) ? *(const bf16x8*)&Msh[st*16 + fr][256]
                          : (bf16x8){0,0,0,0,0,0,0,0};
      sacc[st] = __builtin_amdgcn_mfma_f32_16x16x32_bf16(aqh, bq, sacc[st], 0, 0, 0);
      sacc[st] = __builtin_amdgcn_mfma_f32_16x16x32_bf16(aql, bq, sacc[st], 0, 0, 0);
    }
  }

  #pragma unroll
  for (int r = 0; r < 4; ++r) {
    float tv[7];
    #pragma unroll
    for (int st = 0; st < 7; ++st) {
      const float e2 = __expf(2.f * sacc[st][r]);
      tv[st] = 1.f - 2.f / (e2 + 1.f);
    }
    if (fr >= 14) tv[6] = -3.0e38f;
    float mx = fmaxf(fmaxf(fmaxf(tv[0],tv[1]), fmaxf(tv[2],tv[3])),
                     fmaxf(fmaxf(tv[4],tv[5]), tv[6]));
    #pragma unroll
    for (int o = 8; o >= 1; o >>= 1) mx = fmaxf(mx, __shfl_xor(mx, o, 16));
    float e[7], sum = 0.f;
    #pragma unroll
    for (int st = 0; st < 7; ++st) { e[st] = __expf(tv[st] - mx); sum += e[st]; }
    #pragma unroll
    for (int o = 8; o >= 1; o >>= 1) sum += __shfl_xor(sum, o, 16);
    const float inv = 1.f / sum;
    const int tr = t0 + (g << 2) + r;
    #pragma unroll
    for (int st = 0; st < 7; ++st) Ash[tr][st*16 + fr] = (__bf16)(e[st] * inv);
  }
  __syncthreads();

  const int tr2 = t0 + (g << 2);
  for (int dt = 0; dt < 17; ++dt) {
    const int d0 = dt << 4;
    f32x4 pacc = (f32x4){0.f,0.f,0.f,0.f};
    #pragma unroll
    for (int kst = 0; kst < 4; ++kst) {
      const int k0 = kst << 5;
      const bf16x8 pa = *(const bf16x8*)&Ash [t0 + fr][k0 + fk];
      const bf16x8 pb = *(const bf16x8*)&MTsh[d0 + fr][k0 + fk];
      pacc = __builtin_amdgcn_mfma_f32_16x16x32_bf16(pa, pb, pacc, 0, 0, 0);
    }
    const int col = d0 + fr;
    if (col < 264) {
      #pragma unroll
      for (int r = 0; r < 4; ++r) {
        const int t = tr2 + r;
        if (t < TT) att[((size_t)t * BBD + b) * 264 + col] = (__bf16)pacc[r];
      }
    }
  }
}

// ---------------------------------------------------------------------------
// final_k: fused hidden GEMM (att@Wl+bl, ReLU) + logits + log_softmax.
// ---------------------------------------------------------------------------
__global__ __launch_bounds__(256) void final_k(
    const __bf16* __restrict__ att, const __bf16* __restrict__ Wlimg,
    const float* __restrict__ bl, const float* __restrict__ Wsm,
    const float* __restrict__ bsm, float* __restrict__ out)
{
  constexpr int KSP = 320;
  __shared__ __align__(16) __bf16 Bsh[64][KSP];
  __shared__ float hidf[64][68];
  __shared__ float Wssh[64][8];
  const int tid = threadIdx.x;
  const int bid = blockIdx.x;
  const int m0 = ((bid & 7) * 55 + (bid >> 3)) << 6;   // 440 = 8*55
  {
    const bf16x8* src = (const bf16x8*)Wlimg;
    bf16x8* dst = (bf16x8*)&Bsh[0][0];
    #pragma unroll
    for (int c = 0; c < 10; ++c) dst[c * 256 + tid] = src[c * 256 + tid];
    for (int i = tid; i < 512; i += 256) {
      const int k = i >> 3, cc = i & 7;
      Wssh[k][cc] = (cc < 7) ? Wsm[k*7 + cc] : 0.f;
    }
  }
  __syncthreads();
  const int wid = tid >> 6, lane = tid & 63;
  const int wm = wid >> 1, wn = wid & 1;
  const int fr = lane & 15, fk = (lane >> 4) << 3, row0 = (lane >> 4) << 2;
  f32x4 acc[2][2];
  #pragma unroll
  for (int f = 0; f < 2; ++f)
    #pragma unroll
    for (int g = 0; g < 2; ++g) acc[f][g] = (f32x4){0.f,0.f,0.f,0.f};
  #pragma unroll
  for (int kt = 0; kt < 9; ++kt) {
    const int ko = (kt << 5) + fk;
    bf16x8 af[2];
    #pragma unroll
    for (int f = 0; f < 2; ++f) {
      const int ra = m0 + wm*32 + f*16 + fr;
      af[f] = (ko < 264) ? *(const bf16x8*)(att + (size_t)ra*264 + ko)
                         : (bf16x8){0,0,0,0,0,0,0,0};
    }
    bf16x8 bfv[2];
    #pragma unroll
    for (int g = 0; g < 2; ++g) {
      const int rb_ = wn*32 + g*16 + fr;
      bfv[g] = *(const bf16x8*)&Bsh[rb_][(((ko >> 3) ^ (rb_ & 7)) << 3)];
    }
    #pragma unroll
    for (int f = 0; f < 2; ++f)
      #pragma unroll
      for (int g = 0; g < 2; ++g)
        acc[f][g] = __builtin_amdgcn_mfma_f32_16x16x32_bf16(af[f], bfv[g], acc[f][g], 0, 0, 0);
  }
  // hidden tile -> LDS (ReLU + bias)
  #pragma unroll
  for (int g = 0; g < 2; ++g) {
    const int col = wn*32 + g*16 + fr;
    const float bv = bl[col];
    #pragma unroll
    for (int f = 0; f < 2; ++f) {
      const int lr0 = wm*32 + f*16 + row0;
      #pragma unroll
      for (int r2 = 0; r2 < 4; ++r2)
        hidf[lr0 + r2][col] = fmaxf(acc[f][g][r2] + bv, 0.f);
    }
  }
  __syncthreads();
  // logits + log_softmax: 2 passes of 32 rows, 8 lanes per row
  const int c = tid & 7;
  const float bc = (c < 7) ? bsm[c] : 0.f;
  #pragma unroll
  for (int p = 0; p < 2; ++p) {
    const int lr = (p << 5) + (tid >> 3);
    float lg = -3.0e38f;
    if (c < 7) {
      lg = bc;
      #pragma unroll
      for (int k = 0; k < 64; ++k) lg += hidf[lr][k] * Wssh[k][c];
    }
    float mx = lg;
    #pragma unroll
    for (int o = 4; o >= 1; o >>= 1) mx = fmaxf(mx, __shfl_xor(mx, o, 8));
    float e = (c < 7) ? __expf(lg - mx) : 0.f;
    float sm = e;
    #pragma unroll
    for (int o = 4; o >= 1; o >>= 1) sm += __shfl_xor(sm, o, 8);
    if (c < 7) {
      const int gm = m0 + lr;                 // gm = t*256 + b
      const int t = gm >> 8, bb = gm & 255;
      out[((size_t)bb * TT + t) * 7 + c] = lg - mx - __logf(sm);
    }
  }
}

// ---------------------------------------------------------------------------
extern "C" void kernel_launch(void* const* d_in, const int* in_sizes, int n_in,
                              void* d_out, int out_size, void* d_ws, size_t ws_size,
                              hipStream_t stream)
{
  const float* textf  = (const float*)d_in[0];
  const float* acouf  = (const float*)d_in[1];
  const float* visuf  = (const float*)d_in[2];
  const int*   spk    = (const int*)  d_in[3];
  const float* Wf     = (const float*)d_in[4];
  const float* bfv    = (const float*)d_in[5];
  const float* basis  = (const float*)d_in[6];
  const float* comp   = (const float*)d_in[7];
  const float* root   = (const float*)d_in[8];
  const float* brg    = (const float*)d_in[9];
  const float* Wrel   = (const float*)d_in[10];
  const float* brel   = (const float*)d_in[11];
  const float* Wroot2 = (const float*)d_in[12];
  const float* Wma    = (const float*)d_in[13];
  const float* bma    = (const float*)d_in[14];
  const float* Wl     = (const float*)d_in[15];
  const float* bl     = (const float*)d_in[16];
  const float* Wsm    = (const float*)d_in[17];
  const float* bsm    = (const float*)d_in[18];

  float* ws = (float*)d_ws;
  float*  wrels = ws;                               // @0        (115,200 f32)
  __bf16* img   = (__bf16*)(ws + 115200);           // 360,448 bf16 images
  __bf16* Ain   = (__bf16*)(ws + 295424);           // N*320 bf16
  __bf16* xb    = (__bf16*)(ws + 4801024);          // N*200 bf16
  __bf16* xr    = (__bf16*)(ws + 7617024);          // N*576 bf16 (att aliases)
  __bf16* h2    = (__bf16*)(ws + 15727104);         // N*64 bf16
  __bf16* Xqb   = (__bf16*)(ws + 16628224);         // 2*N*288 bf16
  __bf16* attb  = xr;                               // alias (dead after dialog_k)
  float*  outp  = (float*)d_out;

  __bf16* Wfimg  = img;
  __bf16* wrimg  = img + 81920;
  __bf16* Wmaimg = img + 229376;
  __bf16* Wlimg  = img + 331776;
  __bf16* Wgcimg = img + 352256;

  wrels_k<<<450, 256, 0, stream>>>(basis, comp, root, wrels);
  prep_k<<<2048, 256, 0, stream>>>(textf, acouf, visuf, wrels, Wf, Wma, Wl,
                                   Wrel, Wroot2, Ain, img);
  bgemm_k<0,10,320,4,1><<<1760, 256, 0, stream>>>(Ain, nullptr, Wfimg, bfv, xb, 200);
  bgemm_k<1,7,256,9,1><<<3960, 256, 0, stream>>>(xb, nullptr, wrimg, nullptr, xr, 576);
  dialog_k<<<256, 512, 0, stream>>>(xr, spk, brg, Wgcimg, brel, h2);
  bgemm_k<2,9,320,5,2><<<2200, 256, 0, stream>>>(xb, h2, Wmaimg, bma, Xqb, 264);
  attn_mfma_k<<<256, 448, 0, stream>>>(xb, h2, Xqb, attb);
  final_k<<<440, 256, 0, stream>>>(attb, Wlimg, bl, Wsm, bsm, outp);
}

// Round 12
// 174.326 us; speedup vs baseline: 2.8067x; 1.0429x over previous
//
#include <hip/hip_runtime.h>

#define TT   110          // max_seq_len
#define BBD  256          // num dialogues
#define NND  28160        // TT*BBD
#define WIN  10

typedef __bf16 bf16x8 __attribute__((ext_vector_type(8)));
typedef __bf16 bf16x4 __attribute__((ext_vector_type(4)));
typedef float  f32x4  __attribute__((ext_vector_type(4)));

__device__ __forceinline__ int imax(int a, int b){ return a > b ? a : b; }
__device__ __forceinline__ int imin(int a, int b){ return a < b ? a : b; }

// All per-node matrices are SOURCE-MAJOR: row m = t*256 + b  (node n = b*110+t).
// Weight images (bf16, pre-swizzled per 64-col tile, row=col, KSP elems):
//   Wfimg [4][64][320] @ img+0
//   wrimg [9][64][256] @ img+81920
//   Wmaimg[5][64][320] @ img+229376
//   Wlimg [1][64][320] @ img+331776
//   Wgcimg[1][64][128] @ img+352256
// Image storage: source k-chunk c (8 bf16) stored at chunk position c^(col&7)
// (XOR involution, matches the Bsh read formula ((ko>>3)^(col&7))<<3).

// ---------------------------------------------------------------------------
// K0: Wrels[r][f][h] = sum_nb comp[r][nb]*basis[nb][f][h]  (r<8); Wrels[8]=root
// ---------------------------------------------------------------------------
__global__ __launch_bounds__(256) void wrels_k(
    const float* __restrict__ basis, const float* __restrict__ comp,
    const float* __restrict__ root, float* __restrict__ wrels)
{
  int idx = blockIdx.x * 256 + threadIdx.x;        // 9*12800 = 115200
  if (idx >= 115200) return;
  int r = idx / 12800, fh = idx % 12800;
  float v;
  if (r < 8) {
    v = 0.f;
    #pragma unroll
    for (int nb = 0; nb < 30; ++nb) v += comp[r*30 + nb] * basis[nb*12800 + fh];
  } else {
    v = root[fh];
  }
  wrels[idx] = v;
}

// ---------------------------------------------------------------------------
// prep_k: (a) pack f32 modalities -> Ain[N][320] bf16 (cols 300..319 zero);
// (b) build all bf16 pre-swizzled weight tile images. Grid-stride, streaming.
// ---------------------------------------------------------------------------
__global__ __launch_bounds__(256) void prep_k(
    const float* __restrict__ textf, const float* __restrict__ acouf,
    const float* __restrict__ visuf, const float* __restrict__ wrels,
    const float* __restrict__ Wf, const float* __restrict__ Wma,
    const float* __restrict__ Wl, const float* __restrict__ Wrel,
    const float* __restrict__ Wroot2, __bf16* __restrict__ Ain,
    __bf16* __restrict__ img)
{
  constexpr int T0 = 1126400;            // Ain chunks: N*40
  constexpr int T1 = T0 + 10240;         // Wf   4*64*40
  constexpr int T2 = T1 + 18432;         // wrels 9*64*32
  constexpr int T3 = T2 + 12800;         // Wma  5*64*40
  constexpr int T4 = T3 + 2560;          // Wl   64*40
  constexpr int T5 = T4 + 1024;          // Wgc  64*16
  for (int c = blockIdx.x * 256 + threadIdx.x; c < T5; c += gridDim.x * 256) {
    bf16x8 v;
    __bf16* dst;
    if (c < T0) {
      const int m = c / 40, cc = c - m * 40;
      const int col0 = cc << 3;
      const size_t ab = (size_t)m * 100;
      #pragma unroll
      for (int e = 0; e < 8; ++e) {
        const int col = col0 + e;
        float x = (col < 100) ? textf[ab + col]
                : (col < 200) ? acouf[ab + col - 100]
                : (col < 300) ? visuf[ab + col - 200] : 0.f;
        v[e] = (__bf16)x;
      }
      dst = Ain + (size_t)m * 320 + col0;
    } else if (c < T1) {
      const int r = c - T0;
      const int cb = r / 2560, r2 = r - cb * 2560;
      const int col = r2 / 40, ch = r2 - col * 40;
      const int cs = (ch & ~7) | ((ch ^ col) & 7);
      const int gc = (cb << 6) + col;
      #pragma unroll
      for (int e = 0; e < 8; ++e) {
        const int k = (cs << 3) + e;
        v[e] = (__bf16)((k < 300 && gc < 200) ? Wf[k*200 + gc] : 0.f);
      }
      dst = img + cb * 20480 + col * 320 + (ch << 3);
    } else if (c < T2) {
      const int r = c - T1;
      const int cb = r / 2048, r2 = r - cb * 2048;
      const int col = r2 / 32, ch = r2 - col * 32;
      const int cs = (ch & ~7) | ((ch ^ col) & 7);
      #pragma unroll
      for (int e = 0; e < 8; ++e) {
        const int k = (cs << 3) + e;
        v[e] = (__bf16)((k < 200) ? wrels[cb*12800 + k*64 + col] : 0.f);
      }
      dst = img + 81920 + cb * 16384 + col * 256 + (ch << 3);
    } else if (c < T3) {
      const int r = c - T2;
      const int cb = r / 2560, r2 = r - cb * 2560;
      const int col = r2 / 40, ch = r2 - col * 40;
      const int cs = (ch & ~7) | ((ch ^ col) & 7);
      const int gc = (cb << 6) + col;
      #pragma unroll
      for (int e = 0; e < 8; ++e) {
        const int k = (cs << 3) + e;
        v[e] = (__bf16)((k < 264 && gc < 264) ? Wma[k*264 + gc] : 0.f);
      }
      dst = img + 229376 + cb * 20480 + col * 320 + (ch << 3);
    } else if (c < T4) {
      const int r = c - T3;
      const int col = r / 40, ch = r - col * 40;
      const int cs = (ch & ~7) | ((ch ^ col) & 7);
      #pragma unroll
      for (int e = 0; e < 8; ++e) {
        const int k = (cs << 3) + e;
        v[e] = (__bf16)((k < 264) ? Wl[k*64 + col] : 0.f);
      }
      dst = img + 331776 + col * 320 + (ch << 3);
    } else {
      const int r = c - T4;
      const int col = r / 16, ch = r - col * 16;
      const int cs = (ch & ~7) | ((ch ^ col) & 7);
      #pragma unroll
      for (int e = 0; e < 8; ++e) {
        const int k = (cs << 3) + e;
        v[e] = (__bf16)((k < 64) ? Wrel[k*64 + col] : Wroot2[(k-64)*64 + col]);
      }
      dst = img + 352256 + col * 128 + (ch << 3);
    }
    *(bf16x8*)dst = v;
  }
}

// ---------------------------------------------------------------------------
// bgemm: B-resident MFMA GEMM, bf16 A + pre-swizzled B image.
// ---------------------------------------------------------------------------
template<int MODE, int NK, int KSP, int NCB, int OUT>
__global__ __launch_bounds__(256) void bgemm_k(
    const __bf16* __restrict__ A0, const __bf16* __restrict__ A1,
    const __bf16* __restrict__ Bimg, const float* __restrict__ bias,
    void* __restrict__ Cv, int Ncols)
{
  __shared__ __align__(16) __bf16 Bsh[64][KSP];
  const int tid = threadIdx.x;
  constexpr int NWT = 440 * NCB;
  constexpr int q = NWT >> 3;
  const int bid = blockIdx.x;
  const int w = (bid & 7) * q + (bid >> 3);          // bijective XCD swizzle
  const int m0 = (w / NCB) << 6;
  const int cb = w % NCB;
  const int n0 = cb << 6;

  { // ---- B tile: linear vector copy of pre-swizzled image ----
    const bf16x8* src = (const bf16x8*)(Bimg + (size_t)cb * (64 * KSP));
    bf16x8* dst = (bf16x8*)&Bsh[0][0];
    constexpr int NIT = (64 * KSP / 8) / 256;
    #pragma unroll
    for (int c = 0; c < NIT; ++c) dst[c * 256 + tid] = src[c * 256 + tid];
  }
  __syncthreads();

  const int wid = tid >> 6, lane = tid & 63;
  const int wm = wid >> 1, wn = wid & 1;
  const int fr = lane & 15;
  const int fk = (lane >> 4) << 3;
  const int row0 = (lane >> 4) << 2;

  f32x4 acc[2][2];
  #pragma unroll
  for (int f = 0; f < 2; ++f)
    #pragma unroll
    for (int g = 0; g < 2; ++g) acc[f][g] = (f32x4){0.f,0.f,0.f,0.f};

  #pragma unroll
  for (int kt = 0; kt < NK; ++kt) {
    const int ko = (kt << 5) + fk;
    bf16x8 af[2];
    #pragma unroll
    for (int f = 0; f < 2; ++f) {
      const int ra = m0 + wm*32 + f*16 + fr;
      if constexpr (MODE == 2) {
        af[f] = (ko < 200) ? *(const bf16x8*)(A0 + (size_t)ra*200 + ko)
                           : *(const bf16x8*)(A1 + (size_t)ra*64 + (ko - 200));
      } else {
        constexpr int SA = (MODE == 0) ? 320 : 200;
        af[f] = *(const bf16x8*)(A0 + (size_t)ra*SA + ko);
      }
    }
    bf16x8 bfv[2];
    #pragma unroll
    for (int g = 0; g < 2; ++g) {
      const int rb_ = wn*32 + g*16 + fr;
      bfv[g] = *(const bf16x8*)&Bsh[rb_][(((ko >> 3) ^ (rb_ & 7)) << 3)];
    }
    #pragma unroll
    for (int f = 0; f < 2; ++f)
      #pragma unroll
      for (int g = 0; g < 2; ++g)
        acc[f][g] = __builtin_amdgcn_mfma_f32_16x16x32_bf16(af[f], bfv[g], acc[f][g], 0, 0, 0);
  }

  // ---- epilogue: D col=lane&15, row=(lane>>4)*4+reg ----
  #pragma unroll
  for (int g = 0; g < 2; ++g) {
    const int col = n0 + wn*32 + g*16 + fr;
    if (col < Ncols) {
      const float bv = bias ? bias[col] : 0.f;
      #pragma unroll
      for (int f = 0; f < 2; ++f) {
        const int gm0 = m0 + wm*32 + f*16 + row0;
        #pragma unroll
        for (int r2 = 0; r2 < 4; ++r2) {
          const float v = acc[f][g][r2] + bv;
          const int gm = gm0 + r2;
          if constexpr (OUT == 1) {
            ((__bf16*)Cv)[(size_t)gm * Ncols + col] = (__bf16)v;
          } else {
            __bf16* Cb = (__bf16*)Cv;
            const size_t o = (size_t)gm * 288 + col;
            const __bf16 hi = (__bf16)v;
            Cb[o] = hi;
            Cb[(size_t)288 * NND + o] = (__bf16)(v - (float)hi);
          }
        }
      }
    }
  }
}

// ---------------------------------------------------------------------------
// dialog_k: fused RGCN mean-agg + window-sum + GraphConv GEMM.
// ROUND 12: TWO blocks per dialogue (t-halves [0,55) / [55,110)), 74.6 KB LDS
// -> 2 blocks/CU (4 waves/SIMD, 2x latency hiding). agg stored bf16 (same
// rounding point as before); Wgc B-fragments read from L2-hot global image;
// speaker prefix-sum via wave-0 shfl scan.
// ---------------------------------------------------------------------------
__global__ __launch_bounds__(512) void dialog_k(
    const __bf16* __restrict__ xr, const int* __restrict__ spk,
    const float* __restrict__ brg, const __bf16* __restrict__ Wgcimg,
    const float* __restrict__ brel, __bf16* __restrict__ h2)
{
  __shared__ __align__(16) __bf16 Xsh[75][320];   // 48000 B: xr rows [XLO, XLO+75)
  __shared__ float  h1f[65][68];                  // 17680 B: h1 rows [H1LO, H1LO+65)
  __shared__ __align__(16) __bf16 aggbf[56][72];  //  8064 B: agg rows [t0, t0+55)
  __shared__ int ssp[TT];
  __shared__ int pc[TT + 1];
  const int bid = blockIdx.x;
  const int b = bid >> 1, half = bid & 1;
  const int t0   = half ? 55 : 0;
  const int H1LO = half ? 45 : 0;
  const int XLO  = half ? 35 : 0;
  const int tid = threadIdx.x;
  if (tid < TT) ssp[tid] = spk[tid * BBD + b];
  __syncthreads();
  // ---- wave 0: inclusive shfl-scan of speakers -> pc[0..110] ----
  if (tid < 64) {
    int v = (tid < TT) ? ssp[tid] : 0;
    #pragma unroll
    for (int o = 1; o < 64; o <<= 1) { const int u = __shfl_up(v, o); if (tid >= o) v += u; }
    pc[tid + 1] = v;
    const int tot = __shfl(v, 63);
    int v2 = (tid + 64 < TT) ? ssp[tid + 64] : 0;
    #pragma unroll
    for (int o = 1; o < 64; o <<= 1) { const int u = __shfl_up(v2, o); if (tid >= o) v2 += u; }
    if (tid + 64 < TT) pc[tid + 65] = tot + v2;
    if (tid == 0) pc[0] = 0;
  }
  // ---- stage xr slices for rows [XLO, XLO+75) ----
  for (int i = tid << 3; i < 75 * 320; i += 512 << 3) {
    const int xl = i / 320, off = i - xl * 320;
    const int j = XLO + xl;
    const size_t base = ((size_t)j * BBD + b) * 576;
    const int col = (off < 256) ? ((ssp[j] << 8) + off) : (256 + off);
    *(bf16x8*)&Xsh[xl][off] = *(const bf16x8*)&xr[base + col];
  }
  __syncthreads();
  const int w8 = tid >> 6, lane = tid & 63;
  const float bias = brg[lane];
  // ---- phase 1: h1 rows [H1LO, H1LO+65), unrolled window, LDS reads ----
  for (int lh = w8; lh < 65; lh += 8) {
    const int t = H1LO + lh;
    const int si2 = ssp[t] << 1;
    float a00 = 0.f, a01 = 0.f, a10 = 0.f, a11 = 0.f;
    #pragma unroll
    for (int dj = -WIN; dj <= WIN; ++dj) {
      const int j = t + dj;
      const int jc = imin(imax(j, XLO), XLO + 74);
      const int cdir = (dj >= 0) ? 1 : 0;
      const float v = (float)Xsh[jc - XLO][((si2 + cdir) << 6) + lane];
      const bool ok = (j >= 0) && (j < TT);
      const float m1 = (ok && ssp[jc] != 0) ? 1.f : 0.f;
      const float m0 = (ok && ssp[jc] == 0) ? 1.f : 0.f;
      if (dj >= 0) { a01 = fmaf(m0, v, a01); a11 = fmaf(m1, v, a11); }
      else         { a00 = fmaf(m0, v, a00); a10 = fmaf(m1, v, a10); }
    }
    const int jlo = imax(t - WIN, 0), jhi = imin(t + WIN, TT - 1);
    const int n1d0 = pc[t] - pc[jlo];
    const int n0d0 = (t - jlo) - n1d0;
    const int n1d1 = pc[jhi + 1] - pc[t];
    const int n0d1 = (jhi - t + 1) - n1d1;
    float res = a00 / (float)imax(n0d0, 1) + a01 / (float)imax(n0d1, 1)
              + a10 / (float)imax(n1d0, 1) + a11 / (float)imax(n1d1, 1);
    res += (float)Xsh[t - XLO][256 + lane] + bias;
    h1f[lh][lane] = res;
  }
  __syncthreads();
  // ---- phase 2: agg rows [t0, t0+55), unrolled; store bf16 ----
  for (int lt = w8; lt < 55; lt += 8) {
    const int t = t0 + lt;
    float a = 0.f;
    #pragma unroll
    for (int dj = -WIN; dj <= WIN; ++dj) {
      const int j = t + dj;
      const int jc = imin(imax(j, H1LO), H1LO + 64);
      const float m = ((j >= 0) && (j < TT)) ? 1.f : 0.f;
      a = fmaf(m, h1f[jc - H1LO][lane], a);
    }
    aggbf[lt][lane] = (__bf16)a;
  }
  __syncthreads();
  // ---- phase 3: h2 tile 64x64 (rows 55..63 zero), waves 0..3 ----
  if (w8 < 4) {
    const int wm = w8 >> 1, wn = w8 & 1;
    const int fr = lane & 15, fk = (lane >> 4) << 3, row0 = (lane >> 4) << 2;
    const int lhh = t0 - H1LO;           // 0 or 10
    f32x4 acc[2][2];
    #pragma unroll
    for (int f = 0; f < 2; ++f)
      #pragma unroll
      for (int g = 0; g < 2; ++g) acc[f][g] = (f32x4){0.f,0.f,0.f,0.f};
    #pragma unroll
    for (int kt = 0; kt < 4; ++kt) {
      const int ko = (kt << 5) + fk;
      bf16x8 af[2];
      #pragma unroll
      for (int f = 0; f < 2; ++f) {
        const int tr = wm*32 + f*16 + fr;
        if (tr < 55) {
          if (ko < 64) {
            af[f] = *(const bf16x8*)&aggbf[tr][ko];
          } else {
            const float* src = &h1f[tr + lhh][ko - 64];
            const float4 u0 = ((const float4*)src)[0];
            const float4 u1 = ((const float4*)src)[1];
            af[f] = (bf16x8){(__bf16)u0.x,(__bf16)u0.y,(__bf16)u0.z,(__bf16)u0.w,
                             (__bf16)u1.x,(__bf16)u1.y,(__bf16)u1.z,(__bf16)u1.w};
          }
        } else af[f] = (bf16x8){0,0,0,0,0,0,0,0};
      }
      bf16x8 bfv[2];
      #pragma unroll
      for (int g = 0; g < 2; ++g) {
        const int rb_ = wn*32 + g*16 + fr;
        bfv[g] = *(const bf16x8*)(Wgcimg + rb_*128 + (((ko >> 3) ^ (rb_ & 7)) << 3));
      }
      #pragma unroll
      for (int f = 0; f < 2; ++f)
        #pragma unroll
        for (int g = 0; g < 2; ++g)
          acc[f][g] = __builtin_amdgcn_mfma_f32_16x16x32_bf16(af[f], bfv[g], acc[f][g], 0, 0, 0);
    }
    #pragma unroll
    for (int g = 0; g < 2; ++g) {
      const int col = wn*32 + g*16 + fr;
      const float bv = brel[col];
      #pragma unroll
      for (int f = 0; f < 2; ++f) {
        const int tr0 = wm*32 + f*16 + row0;
        #pragma unroll
        for (int r2 = 0; r2 < 4; ++r2) {
          const int tr = tr0 + r2;
          if (tr < 55) {
            const int t = t0 + tr;
            h2[((size_t)t * BBD + b) * 64 + col] = (__bf16)(acc[f][g][r2] + bv);
          }
        }
      }
    }
  }
}

// ---------------------------------------------------------------------------
// attn: MFMA matching attention, one block (448 thr = 7 waves) per dialogue.
// ---------------------------------------------------------------------------
__global__ __launch_bounds__(448) void attn_mfma_k(
    const __bf16* __restrict__ x, const __bf16* __restrict__ h2,
    const __bf16* __restrict__ Xq, __bf16* __restrict__ att)
{
  __shared__ __align__(16) __bf16 Msh [TT ][272];
  __shared__ __align__(16) __bf16 MTsh[264][136];
  __shared__ __align__(16) __bf16 Ash [112][136];
  const int b = blockIdx.x;
  const int tid = threadIdx.x;

  for (int idx = tid; idx < TT * 66; idx += 448) {
    const int s = idx / 66, c4 = idx % 66;
    const size_t node = (size_t)s * BBD + b;
    bf16x4 pk;
    if (c4 < 50) pk = *(const bf16x4*)&x [node * 200 + (c4 << 2)];
    else         pk = *(const bf16x4*)&h2[node * 64 + ((c4 - 50) << 2)];
    *(bf16x4*)&Msh[s][c4 << 2] = pk;
    const int d = c4 << 2;
    MTsh[d+0][s] = pk[0]; MTsh[d+1][s] = pk[1];
    MTsh[d+2][s] = pk[2]; MTsh[d+3][s] = pk[3];
  }
  for (int idx = tid; idx < 264 * 26; idx += 448) MTsh[idx / 26][110 + idx % 26] = (__bf16)0.f;
  for (int idx = tid; idx < 112 * 24; idx += 448) Ash[idx / 24][112 + idx % 24] = (__bf16)0.f;
  __syncthreads();

  const int wid = tid >> 6, lane = tid & 63;
  const int t0 = wid << 4;
  const int fr = lane & 15;
  const int g  = lane >> 4;
  const int fk = g << 3;

  f32x4 sacc[7];
  #pragma unroll
  for (int st = 0; st < 7; ++st) sacc[st] = (f32x4){0.f,0.f,0.f,0.f};
  const int trow = t0 + fr;
  const size_t arow = ((size_t)(trow < TT ? trow : TT - 1) * BBD + b) * 288;
  const __bf16* XqLo = Xq + (size_t)288 * NND;
  for (int kst = 0; kst < 9; ++kst) {
    const int k0 = kst << 5;
    bf16x8 aqh = *(const bf16x8*)&Xq  [arow + k0 + fk];
    bf16x8 aql = *(const bf16x8*)&XqLo[arow + k0 + fk];
    if (kst == 8 && fk != 0) {
      aqh = (bf16x8){0,0,0,0,0,0,0,0};
      aql = (bf16x8){0,0,0,0,0,0,0,0};
    }
    #pragma unroll
    for (int st = 0; st < 7; ++st) {
      bf16x8 bq;
      if (kst < 8) bq = *(const bf16x8*)&Msh[st*16 + fr][k0 + fk];
      else bq = (fk == 0) ? *(const bf16x8*)&Msh[st*16 + fr][256]
                          : (bf16x8){0,0,0,0,0,0,0,0};
      sacc[st] = __builtin_amdgcn_mfma_f32_16x16x32_bf16(aqh, bq, sacc[st], 0, 0, 0);
      sacc[st] = __builtin_amdgcn_mfma_f32_16x16x32_bf16(aql, bq, sacc[st], 0, 0, 0);
    }
  }

  #pragma unroll
  for (int r = 0; r < 4; ++r) {
    float tv[7];
    #pragma unroll
    for (int st = 0; st < 7; ++st) {
      const float e2 = __expf(2.f * sacc[st][r]);
      tv[st] = 1.f - 2.f / (e2 + 1.f);
    }
    if (fr >= 14) tv[6] = -3.0e38f;
    float mx = fmaxf(fmaxf(fmaxf(tv[0],tv[1]), fmaxf(tv[2],tv[3])),
                     fmaxf(fmaxf(tv[4],tv[5]), tv[6]));
    #pragma unroll
    for (int o = 8; o >= 1; o >>= 1) mx = fmaxf(mx, __shfl_xor(mx, o, 16));
    float e[7], sum = 0.f;
    #pragma unroll
    for (int st = 0; st < 7; ++st) { e[st] = __expf(tv[st] - mx); sum += e[st]; }
    #pragma unroll
    for (int o = 8; o >= 1; o >>= 1) sum += __shfl_xor(sum, o, 16);
    const float inv = 1.f / sum;
    const int tr = t0 + (g << 2) + r;
    #pragma unroll
    for (int st = 0; st < 7; ++st) Ash[tr][st*16 + fr] = (__bf16)(e[st] * inv);
  }
  __syncthreads();

  const int tr2 = t0 + (g << 2);
  for (int dt = 0; dt < 17; ++dt) {
    const int d0 = dt << 4;
    f32x4 pacc = (f32x4){0.f,0.f,0.f,0.f};
    #pragma unroll
    for (int kst = 0; kst < 4; ++kst) {
      const int k0 = kst << 5;
      const bf16x8 pa = *(const bf16x8*)&Ash [t0 + fr][k0 + fk];
      const bf16x8 pb = *(const bf16x8*)&MTsh[d0 + fr][k0 + fk];
      pacc = __builtin_amdgcn_mfma_f32_16x16x32_bf16(pa, pb, pacc, 0, 0, 0);
    }
    const int col = d0 + fr;
    if (col < 264) {
      #pragma unroll
      for (int r = 0; r < 4; ++r) {
        const int t = tr2 + r;
        if (t < TT) att[((size_t)t * BBD + b) * 264 + col] = (__bf16)pacc[r];
      }
    }
  }
}

// ---------------------------------------------------------------------------
// final_k: fused hidden GEMM (att@Wl+bl, ReLU) + logits + log_softmax.
// ---------------------------------------------------------------------------
__global__ __launch_bounds__(256) void final_k(
    const __bf16* __restrict__ att, const __bf16* __restrict__ Wlimg,
    const float* __restrict__ bl, const float* __restrict__ Wsm,
    const float* __restrict__ bsm, float* __restrict__ out)
{
  constexpr int KSP = 320;
  __shared__ __align__(16) __bf16 Bsh[64][KSP];
  __shared__ float hidf[64][68];
  __shared__ float Wssh[64][8];
  const int tid = threadIdx.x;
  const int bid = blockIdx.x;
  const int m0 = ((bid & 7) * 55 + (bid >> 3)) << 6;   // 440 = 8*55
  {
    const bf16x8* src = (const bf16x8*)Wlimg;
    bf16x8* dst = (bf16x8*)&Bsh[0][0];
    #pragma unroll
    for (int c = 0; c < 10; ++c) dst[c * 256 + tid] = src[c * 256 + tid];
    for (int i = tid; i < 512; i += 256) {
      const int k = i >> 3, cc = i & 7;
      Wssh[k][cc] = (cc < 7) ? Wsm[k*7 + cc] : 0.f;
    }
  }
  __syncthreads();
  const int wid = tid >> 6, lane = tid & 63;
  const int wm = wid >> 1, wn = wid & 1;
  const int fr = lane & 15, fk = (lane >> 4) << 3, row0 = (lane >> 4) << 2;
  f32x4 acc[2][2];
  #pragma unroll
  for (int f = 0; f < 2; ++f)
    #pragma unroll
    for (int g = 0; g < 2; ++g) acc[f][g] = (f32x4){0.f,0.f,0.f,0.f};
  #pragma unroll
  for (int kt = 0; kt < 9; ++kt) {
    const int ko = (kt << 5) + fk;
    bf16x8 af[2];
    #pragma unroll
    for (int f = 0; f < 2; ++f) {
      const int ra = m0 + wm*32 + f*16 + fr;
      af[f] = (ko < 264) ? *(const bf16x8*)(att + (size_t)ra*264 + ko)
                         : (bf16x8){0,0,0,0,0,0,0,0};
    }
    bf16x8 bfv[2];
    #pragma unroll
    for (int g = 0; g < 2; ++g) {
      const int rb_ = wn*32 + g*16 + fr;
      bfv[g] = *(const bf16x8*)&Bsh[rb_][(((ko >> 3) ^ (rb_ & 7)) << 3)];
    }
    #pragma unroll
    for (int f = 0; f < 2; ++f)
      #pragma unroll
      for (int g = 0; g < 2; ++g)
        acc[f][g] = __builtin_amdgcn_mfma_f32_16x16x32_bf16(af[f], bfv[g], acc[f][g], 0, 0, 0);
  }
  // hidden tile -> LDS (ReLU + bias)
  #pragma unroll
  for (int g = 0; g < 2; ++g) {
    const int col = wn*32 + g*16 + fr;
    const float bv = bl[col];
    #pragma unroll
    for (int f = 0; f < 2; ++f) {
      const int lr0 = wm*32 + f*16 + row0;
      #pragma unroll
      for (int r2 = 0; r2 < 4; ++r2)
        hidf[lr0 + r2][col] = fmaxf(acc[f][g][r2] + bv, 0.f);
    }
  }
  __syncthreads();
  // logits + log_softmax: 2 passes of 32 rows, 8 lanes per row
  const int c = tid & 7;
  const float bc = (c < 7) ? bsm[c] : 0.f;
  #pragma unroll
  for (int p = 0; p < 2; ++p) {
    const int lr = (p << 5) + (tid >> 3);
    float lg = -3.0e38f;
    if (c < 7) {
      lg = bc;
      #pragma unroll
      for (int k = 0; k < 64; ++k) lg += hidf[lr][k] * Wssh[k][c];
    }
    float mx = lg;
    #pragma unroll
    for (int o = 4; o >= 1; o >>= 1) mx = fmaxf(mx, __shfl_xor(mx, o, 8));
    float e = (c < 7) ? __expf(lg - mx) : 0.f;
    float sm = e;
    #pragma unroll
    for (int o = 4; o >= 1; o >>= 1) sm += __shfl_xor(sm, o, 8);
    if (c < 7) {
      const int gm = m0 + lr;                 // gm = t*256 + b
      const int t = gm >> 8, bb = gm & 255;
      out[((size_t)bb * TT + t) * 7 + c] = lg - mx - __logf(sm);
    }
  }
}

// ---------------------------------------------------------------------------
extern "C" void kernel_launch(void* const* d_in, const int* in_sizes, int n_in,
                              void* d_out, int out_size, void* d_ws, size_t ws_size,
                              hipStream_t stream)
{
  const float* textf  = (const float*)d_in[0];
  const float* acouf  = (const float*)d_in[1];
  const float* visuf  = (const float*)d_in[2];
  const int*   spk    = (const int*)  d_in[3];
  const float* Wf     = (const float*)d_in[4];
  const float* bfv    = (const float*)d_in[5];
  const float* basis  = (const float*)d_in[6];
  const float* comp   = (const float*)d_in[7];
  const float* root   = (const float*)d_in[8];
  const float* brg    = (const float*)d_in[9];
  const float* Wrel   = (const float*)d_in[10];
  const float* brel   = (const float*)d_in[11];
  const float* Wroot2 = (const float*)d_in[12];
  const float* Wma    = (const float*)d_in[13];
  const float* bma    = (const float*)d_in[14];
  const float* Wl     = (const float*)d_in[15];
  const float* bl     = (const float*)d_in[16];
  const float* Wsm    = (const float*)d_in[17];
  const float* bsm    = (const float*)d_in[18];

  float* ws = (float*)d_ws;
  float*  wrels = ws;                               // @0        (115,200 f32)
  __bf16* img   = (__bf16*)(ws + 115200);           // 360,448 bf16 images
  __bf16* Ain   = (__bf16*)(ws + 295424);           // N*320 bf16
  __bf16* xb    = (__bf16*)(ws + 4801024);          // N*200 bf16
  __bf16* xr    = (__bf16*)(ws + 7617024);          // N*576 bf16 (att aliases)
  __bf16* h2    = (__bf16*)(ws + 15727104);         // N*64 bf16
  __bf16* Xqb   = (__bf16*)(ws + 16628224);         // 2*N*288 bf16
  __bf16* attb  = xr;                               // alias (dead after dialog_k)
  float*  outp  = (float*)d_out;

  __bf16* Wfimg  = img;
  __bf16* wrimg  = img + 81920;
  __bf16* Wmaimg = img + 229376;
  __bf16* Wlimg  = img + 331776;
  __bf16* Wgcimg = img + 352256;

  wrels_k<<<450, 256, 0, stream>>>(basis, comp, root, wrels);
  prep_k<<<2048, 256, 0, stream>>>(textf, acouf, visuf, wrels, Wf, Wma, Wl,
                                   Wrel, Wroot2, Ain, img);
  bgemm_k<0,10,320,4,1><<<1760, 256, 0, stream>>>(Ain, nullptr, Wfimg, bfv, xb, 200);
  bgemm_k<1,7,256,9,1><<<3960, 256, 0, stream>>>(xb, nullptr, wrimg, nullptr, xr, 576);
  dialog_k<<<512, 512, 0, stream>>>(xr, spk, brg, Wgcimg, brel, h2);
  bgemm_k<2,9,320,5,2><<<2200, 256, 0, stream>>>(xb, h2, Wmaimg, bma, Xqb, 264);
  attn_mfma_k<<<256, 448, 0, stream>>>(xb, h2, Xqb, attb);
  final_k<<<440, 256, 0, stream>>>(attb, Wlimg, bl, Wsm, bsm, outp);
}